// Round 15
// baseline (202.676 us; speedup 1.0000x reference)
//
#include <hip/hip_runtime.h>
#include <cstdint>
#include <cstddef>

typedef unsigned short u16;
typedef unsigned int   u32;
typedef unsigned char  u8;
typedef __attribute__((ext_vector_type(8))) short short8;
typedef __attribute__((ext_vector_type(8))) u16   u16x8;
typedef __attribute__((ext_vector_type(4))) float f32x4;
typedef __attribute__((ext_vector_type(2))) float f32x2;
typedef __attribute__((ext_vector_type(4))) u16   u16x4;

// ---------- bf16 helpers (RNE) ----------
__device__ __forceinline__ float bf2f(u16 u){
  u32 x = ((u32)u) << 16; float f; __builtin_memcpy(&f, &x, 4); return f;
}
__device__ __forceinline__ u16 f2bf(float f){
  u32 x; __builtin_memcpy(&x, &f, 4);
  x += 0x7fffu + ((x >> 16) & 1u);
  return (u16)(x >> 16);
}

__device__ __forceinline__ void gload_lds16(const u16* g, u16* l){
  __builtin_amdgcn_global_load_lds((const __attribute__((address_space(1))) void*)g,
                                   (__attribute__((address_space(3))) void*)l, 16, 0, 0);
}

// ---------- prep: blocks 0-3 compute Gt = M2 @ M1^T; blocks 4-227 convert weights ----------
__global__ __launch_bounds__(256)
void prep(const float* __restrict__ M2v, const float* __restrict__ M1v,
          const float* __restrict__ W1, const float* __restrict__ W2,
          const float* __restrict__ W3, const float* __restrict__ Wd1,
          const float* __restrict__ Wd2,
          u16* __restrict__ Gtb, u16* __restrict__ W1b, u16* __restrict__ Wcb,
          u16* __restrict__ Wd1b, u16* __restrict__ Wd2b)
{
  __shared__ u16 lds[32768];
  const int tid = threadIdx.x;
  if (blockIdx.x >= 4){
    int j = (blockIdx.x - 4) * 256 + tid;
    const float* src; u16* dst;
    if (j < 16384)                { src = W1;  dst = W1b; }
    else if ((j -= 16384) < 8192) { src = W2;  dst = Wcb; }
    else if ((j -= 8192)  < 8192) { src = W3;  dst = Wcb + 32768; }
    else if ((j -= 8192)  < 8192) { src = Wd1; dst = Wd1b; }
    else { j -= 8192; src = Wd2; dst = Wd2b; }
    float4 v = ((const float4*)src)[j];
    u16x4 o; o[0]=f2bf(v.x); o[1]=f2bf(v.y); o[2]=f2bf(v.z); o[3]=f2bf(v.w);
    ((u16x4*)dst)[j] = o;
    return;
  }
  u16* As0 = lds;         u16* As1 = lds + 8192;
  u16* Bs0 = lds + 16384; u16* Bs1 = lds + 24576;
  const int lane = tid & 63;
  const int wave = tid >> 6;
  const int wm = wave >> 1, wn = wave & 1;
  const int m0 = (blockIdx.x >> 1) << 7, n0 = (blockIdx.x & 1) << 7;

  f32x4 acc[4][4];
  #pragma unroll
  for (int a = 0; a < 4; ++a)
    #pragma unroll
    for (int b = 0; b < 4; ++b)
      acc[a][b] = (f32x4){0.f, 0.f, 0.f, 0.f};

  auto stage = [&](int buf, int kt){
    const int k0 = kt * 64;
    u16* Ad = buf ? As1 : As0;
    u16* Bd = buf ? Bs1 : Bs0;
    const int f = tid * 32;
    {
      const float* sA = M2v + (size_t)(m0 + (f >> 6)) * 256 + k0 + (f & 63);
      u16 t[32];
      #pragma unroll
      for (int q = 0; q < 8; ++q){
        float4 v = *(const float4*)(sA + q * 4);
        t[q*4]=f2bf(v.x); t[q*4+1]=f2bf(v.y); t[q*4+2]=f2bf(v.z); t[q*4+3]=f2bf(v.w);
      }
      #pragma unroll
      for (int q = 0; q < 4; ++q)
        *(u16x8*)(&Ad[f + q*8]) = *(const u16x8*)(&t[q*8]);
    }
    {
      const float* sB = M1v + (size_t)(n0 + (f >> 6)) * 256 + k0 + (f & 63);
      u16 t[32];
      #pragma unroll
      for (int q = 0; q < 8; ++q){
        float4 v = *(const float4*)(sB + q * 4);
        t[q*4]=f2bf(v.x); t[q*4+1]=f2bf(v.y); t[q*4+2]=f2bf(v.z); t[q*4+3]=f2bf(v.w);
      }
      #pragma unroll
      for (int q = 0; q < 4; ++q)
        *(u16x8*)(&Bd[f + q*8]) = *(const u16x8*)(&t[q*8]);
    }
  };

  stage(0, 0);
  __syncthreads();
  int cur = 0;
  for (int kt = 0; kt < 4; ++kt){
    if (kt < 3) stage(cur ^ 1, kt + 1);
    const u16* as = cur ? As1 : As0;
    const u16* bs = cur ? Bs1 : Bs0;
    #pragma unroll
    for (int kk = 0; kk < 2; ++kk){
      const int ko = kk * 32 + (lane >> 4) * 8;
      short8 af[4], bq[4];
      #pragma unroll
      for (int mi = 0; mi < 4; ++mi)
        af[mi] = *(const short8*)(as + (wm*64 + mi*16 + (lane & 15)) * 64 + ko);
      #pragma unroll
      for (int ni = 0; ni < 4; ++ni)
        bq[ni] = *(const short8*)(bs + (wn*64 + ni*16 + (lane & 15)) * 64 + ko);
      #pragma unroll
      for (int mi = 0; mi < 4; ++mi)
        #pragma unroll
        for (int ni = 0; ni < 4; ++ni)
          acc[mi][ni] = __builtin_amdgcn_mfma_f32_16x16x32_bf16(af[mi], bq[ni], acc[mi][ni], 0, 0, 0);
    }
    __syncthreads();
    cur ^= 1;
  }

  const int rbase = m0 + wm * 64 + ((lane >> 4) << 2);
  const int cbase = n0 + wn * 64 + (lane & 15);
  #pragma unroll
  for (int mi = 0; mi < 4; ++mi)
    #pragma unroll
    for (int ni = 0; ni < 4; ++ni){
      const int col = cbase + ni * 16;
      #pragma unroll
      for (int r = 0; r < 4; ++r)
        Gtb[(size_t)(rbase + mi * 16 + r) * 256 + col] = f2bf(acc[mi][ni][r]);
    }
}

// ---------- gather-mean over 20 sampled fp8 rows + relu -> fp8 out ----------
__global__ void gather_fp8(const u32* __restrict__ rows, const int* __restrict__ idx,
                           u32* __restrict__ out, int nout){
  const int pair = blockIdx.x * 4 + (threadIdx.x >> 6);
  const int lane = threadIdx.x & 63;
  const int node0 = pair * 2;
  if (node0 >= nout) return;
  const int half = lane >> 5, l31 = lane & 31;
  const int node = node0 + half;
  const int jv = (l31 < 20) ? idx[(size_t)node * 20 + l31] : 0;
  float a[8];
  #pragma unroll
  for (int k = 0; k < 8; ++k) a[k] = 0.f;
  #pragma unroll
  for (int s = 0; s < 20; ++s){
    const int j = __shfl(jv, (lane & 32) + s, 64);
    const uint2 u = *(const uint2*)(rows + (size_t)j * 64 + l31 * 2);
    f32x2 p0 = __builtin_amdgcn_cvt_pk_f32_fp8((int)u.x, false);
    f32x2 p1 = __builtin_amdgcn_cvt_pk_f32_fp8((int)u.x, true);
    f32x2 p2 = __builtin_amdgcn_cvt_pk_f32_fp8((int)u.y, false);
    f32x2 p3 = __builtin_amdgcn_cvt_pk_f32_fp8((int)u.y, true);
    a[0]+=p0[0]; a[1]+=p0[1]; a[2]+=p1[0]; a[3]+=p1[1];
    a[4]+=p2[0]; a[5]+=p2[1]; a[6]+=p3[0]; a[7]+=p3[1];
  }
  const float inv = 0.05f;
  #pragma unroll
  for (int k = 0; k < 8; ++k) a[k] = fmaxf(a[k] * inv, 0.f);
  const int w0 = __builtin_amdgcn_cvt_pk_fp8_f32(a[0], a[1], 0, false);
  const int w1 = __builtin_amdgcn_cvt_pk_fp8_f32(a[2], a[3], 0, false);
  const int w2 = __builtin_amdgcn_cvt_pk_fp8_f32(a[4], a[5], 0, false);
  const int w3 = __builtin_amdgcn_cvt_pk_fp8_f32(a[6], a[7], 0, false);
  uint2 o;
  o.x = (w0 & 0xffffu) | ((u32)(w1 & 0xffffu) << 16);
  o.y = (w2 & 0xffffu) | ((u32)(w3 & 0xffffu) << 16);
  *(uint2*)(out + (size_t)node * 64 + l31 * 2) = o;
}

// ---------- adj = A[8192,256] @ B[8192,256]^T -> f32 [8192,8192] ----------
__global__ __launch_bounds__(512)
void adj_gemm(const u16* __restrict__ A, const u16* __restrict__ B,
              float* __restrict__ C)
{
  __shared__ __align__(16) u16 lds[32768];        // 64 KB: As 16384 | Bs 16384
  u16* As = lds;
  u16* Bs = lds + 16384;
  const int tid  = threadIdx.x;
  const int lane = tid & 63;
  const int wave = tid >> 6;
  const int wm = wave >> 2, wn = wave & 3;
  const int bid  = blockIdx.x;
  const int xcd  = bid & 7, slot = bid >> 3;
  const int m0 = ((xcd << 2) + (slot >> 5)) << 8;
  const int n0 = (slot & 31) << 8;

  f32x4 acc[8][4];
  #pragma unroll
  for (int a = 0; a < 8; ++a)
    #pragma unroll
    for (int b = 0; b < 4; ++b)
      acc[a][b] = (f32x4){0.f, 0.f, 0.f, 0.f};

  for (int kt = 0; kt < 4; ++kt){
    const int k0 = kt * 64;
    #pragma unroll
    for (int c = 0; c < 4; ++c){
      const int f = c * 4096 + tid * 8;
      const int row = f >> 6, ksw = (f & 63) ^ ((row & 7) << 3);
      gload_lds16(A + (size_t)(m0 + row) * 256 + k0 + ksw, As + f);
    }
    #pragma unroll
    for (int c = 0; c < 4; ++c){
      const int f = c * 4096 + tid * 8;
      const int row = f >> 6, ksw = (f & 63) ^ ((row & 7) << 3);
      gload_lds16(B + (size_t)(n0 + row) * 256 + k0 + ksw, Bs + f);
    }
    __syncthreads();
    #pragma unroll
    for (int kk = 0; kk < 2; ++kk){
      const int ko = kk * 32 + (lane >> 4) * 8;
      short8 af[8], bq[4];
      #pragma unroll
      for (int mi = 0; mi < 8; ++mi){
        const int row = wm*128 + mi*16 + (lane & 15);
        af[mi] = *(const short8*)(As + row * 64 + (ko ^ ((row & 7) << 3)));
      }
      #pragma unroll
      for (int ni = 0; ni < 4; ++ni){
        const int row = wn*64 + ni*16 + (lane & 15);
        bq[ni] = *(const short8*)(Bs + row * 64 + (ko ^ ((row & 7) << 3)));
      }
      #pragma unroll
      for (int mi = 0; mi < 8; ++mi)
        #pragma unroll
        for (int ni = 0; ni < 4; ++ni)
          acc[mi][ni] = __builtin_amdgcn_mfma_f32_16x16x32_bf16(af[mi], bq[ni], acc[mi][ni], 0, 0, 0);
    }
    __syncthreads();
  }

  // epilogue: 8 chunks of 32 rows via LDS transpose (T[32][260] f32 = 33 KB)
  float* T = (float*)lds;
  #pragma unroll
  for (int c = 0; c < 8; ++c){
    if (wm == (c >> 2)){
      #pragma unroll
      for (int mi2 = 0; mi2 < 2; ++mi2){
        const int mi = (c & 3) * 2 + mi2;
        #pragma unroll
        for (int ni = 0; ni < 4; ++ni){
          const int cl = wn*64 + ni*16 + (lane & 15);
          #pragma unroll
          for (int r = 0; r < 4; ++r){
            const int lr = mi2*16 + ((lane >> 4) << 2) + r;
            T[lr * 260 + cl] = acc[mi][ni][r];
          }
        }
      }
    }
    __syncthreads();
    #pragma unroll
    for (int q = 0; q < 4; ++q){
      const int g = q * 512 + tid;
      const int r = g >> 6, col = (g & 63) * 4;
      f32x4 v = *(const f32x4*)(T + r * 260 + col);
      __builtin_nontemporal_store(v, (f32x4*)(C + (size_t)(m0 + c*32 + r) * 8192 + n0 + col));
    }
    __syncthreads();
  }
}

// ---------- FW = F @ W1^T : 128x256 tile, BK=32, fp8 out ----------
__global__ __launch_bounds__(256)
void fw_gemm(const float* __restrict__ A, const u16* __restrict__ B,
             u8* __restrict__ C, int M)
{
  __shared__ u16 lds[26624];   // As 2x5120 (128 x pad40), Bs 2x8192 (256x32)
  u16* As0 = lds;         u16* As1 = lds + 5120;
  u16* Bs0 = lds + 10240; u16* Bs1 = lds + 18432;
  const int tid  = threadIdx.x;
  const int lane = tid & 63;
  const int wave = tid >> 6;
  const int wm = wave >> 1, wn = wave & 1;
  const int m0 = blockIdx.x << 7;

  f32x4 acc[4][8];
  #pragma unroll
  for (int a = 0; a < 4; ++a)
    #pragma unroll
    for (int b = 0; b < 8; ++b)
      acc[a][b] = (f32x4){0.f, 0.f, 0.f, 0.f};

  auto stage = [&](int buf, int kt){
    const int k0 = kt * 32;
    u16* Ad = buf ? As1 : As0;
    u16* Bd = buf ? Bs1 : Bs0;
    const int f = tid * 16;
    const int row = f >> 5, ku = f & 31;
    int ra = m0 + row; if (ra >= M) ra = M - 1;
    const float* sA = A + (size_t)ra * 256 + k0 + ku;
    u16 t[16];
    #pragma unroll
    for (int q = 0; q < 4; ++q){
      float4 v = *(const float4*)(sA + q * 4);
      t[q*4]=f2bf(v.x); t[q*4+1]=f2bf(v.y); t[q*4+2]=f2bf(v.z); t[q*4+3]=f2bf(v.w);
    }
    u16* dA = Ad + row * 40 + ku;
    *(u16x8*)(dA)     = *(const u16x8*)(&t[0]);
    *(u16x8*)(dA + 8) = *(const u16x8*)(&t[8]);
    #pragma unroll
    for (int c = 0; c < 4; ++c){
      const int g = c * 2048 + tid * 8;
      const int rb = g >> 5, kb = g & 31;
      gload_lds16(B + (size_t)rb * 256 + k0 + (kb ^ ((rb & 3) << 3)),
                  Bd + c * 2048 + wave * 512);
    }
  };

  stage(0, 0);
  __syncthreads();
  int cur = 0;
  for (int kt = 0; kt < 8; ++kt){
    if (kt + 1 < 8) stage(cur ^ 1, kt + 1);
    const u16* as = cur ? As1 : As0;
    const u16* bs = cur ? Bs1 : Bs0;
    const int ko = (lane >> 4) * 8;
    short8 af[4], bq[8];
    #pragma unroll
    for (int mi = 0; mi < 4; ++mi)
      af[mi] = *(const short8*)(as + (wm*64 + mi*16 + (lane & 15)) * 40 + ko);
    #pragma unroll
    for (int ni = 0; ni < 8; ++ni){
      const int row = wn*128 + ni*16 + (lane & 15);
      bq[ni] = *(const short8*)(bs + row * 32 + (ko ^ ((row & 3) << 3)));
    }
    #pragma unroll
    for (int mi = 0; mi < 4; ++mi)
      #pragma unroll
      for (int ni = 0; ni < 8; ++ni)
        acc[mi][ni] = __builtin_amdgcn_mfma_f32_16x16x32_bf16(af[mi], bq[ni], acc[mi][ni], 0, 0, 0);
    __syncthreads();
    cur ^= 1;
  }

  const int rbase = m0 + wm * 64 + ((lane >> 4) << 2);
  const int cbase = wn * 128 + (lane & 15);
  #pragma unroll
  for (int mi = 0; mi < 4; ++mi)
    #pragma unroll
    for (int ni = 0; ni < 8; ++ni){
      const int col = cbase + ni * 16;
      #pragma unroll
      for (int r = 0; r < 4; ++r){
        const int row = rbase + mi * 16 + r;
        if (row < M){
          const float v = acc[mi][ni][r];
          const int pk = __builtin_amdgcn_cvt_pk_fp8_f32(v, v, 0, false);
          C[(size_t)row * 256 + col] = (u8)(pk & 0xff);
        }
      }
    }
}

// ---------- fused decoder (in-kernel gather2 over fp8 h1): 16 rows/block, 512 blocks ----------
__global__ __launch_bounds__(256)
void decoder(const u32* __restrict__ h1, const int* __restrict__ neigh2,
             const u16* __restrict__ Wcb,
             const u16* __restrict__ Wd1b, const u16* __restrict__ Wd2b,
             const u16* __restrict__ Gtb, const float* __restrict__ eps,
             const float* __restrict__ b1, const float* __restrict__ b2,
             float* __restrict__ outMu, float* __restrict__ outLv,
             u16* __restrict__ o2g, u16* __restrict__ tmpg)
{
  __shared__ u16 lds[38912];           // S0 16384 | S1 16384 | H 2048 | O1 4096  (76 KB)
  u16* S0 = lds;
  u16* S1 = lds + 16384;
  u16* H  = lds + 32768;               // 2 chunks of 1024 (16x64)
  u16* O1 = lds + 34816;               // 4 chunks of 1024; holds agg2 during enc
  const int tid = threadIdx.x;
  const int lane = tid & 63, wave = tid >> 6;
  const int m0 = blockIdx.x << 4;      // 16 rows/block

  auto stageB = [&](const u16* G, int K, int k0, u16* dst){
    const int fb = wave * 4096 + lane * 8;
    #pragma unroll
    for (int c = 0; c < 8; ++c){
      int f = fb + c * 512;
      gload_lds16(G + (size_t)(f >> 6) * K + k0 + (f & 63), dst + wave*4096 + c*512);
    }
  };
  auto mstep16 = [&](const u16* aC, const u16* bT, f32x4 (&acc)[4]){
    #pragma unroll
    for (int kk = 0; kk < 2; ++kk){
      const int ko = kk * 32 + (lane >> 4) * 8;
      short8 af = *(const short8*)(aC + (lane & 15) * 64 + ko);
      #pragma unroll
      for (int ni = 0; ni < 4; ++ni){
        short8 bq = *(const short8*)(bT + (wave*64 + ni*16 + (lane & 15)) * 64 + ko);
        acc[ni] = __builtin_amdgcn_mfma_f32_16x16x32_bf16(af, bq, acc[ni], 0, 0, 0);
      }
    }
  };

  // ===== in-kernel gather2 over fp8 h1: 2 nodes/wave x 2 iters -> O1 [4][16][64] =====
  {
    const int half = lane >> 5, l31 = lane & 31;
    #pragma unroll
    for (int it = 0; it < 2; ++it){
      const int lrow = it * 8 + wave * 2 + half;      // 0..15 over both iters
      const int node = m0 + lrow;
      const int jv = (l31 < 20) ? neigh2[(size_t)node * 20 + l31] : 0;
      float a[8];
      #pragma unroll
      for (int k = 0; k < 8; ++k) a[k] = 0.f;
      #pragma unroll
      for (int s = 0; s < 20; ++s){
        const int j = __shfl(jv, (lane & 32) + s, 64);
        const uint2 u = *(const uint2*)(h1 + (size_t)j * 64 + l31 * 2);
        f32x2 p0 = __builtin_amdgcn_cvt_pk_f32_fp8((int)u.x, false);
        f32x2 p1 = __builtin_amdgcn_cvt_pk_f32_fp8((int)u.x, true);
        f32x2 p2 = __builtin_amdgcn_cvt_pk_f32_fp8((int)u.y, false);
        f32x2 p3 = __builtin_amdgcn_cvt_pk_f32_fp8((int)u.y, true);
        a[0]+=p0[0]; a[1]+=p0[1]; a[2]+=p1[0]; a[3]+=p1[1];
        a[4]+=p2[0]; a[5]+=p2[1]; a[6]+=p3[0]; a[7]+=p3[1];
      }
      const float inv = 0.05f;
      u16x8 o;
      #pragma unroll
      for (int k = 0; k < 8; ++k) o[k] = f2bf(a[k] * inv);
      const int c0 = l31 * 8;
      *(u16x8*)(O1 + (c0 >> 6) * 1024 + lrow * 64 + (c0 & 63)) = o;
    }
  }

  // ===== enc ===== wave covers cols wave*32..+31 of BOTH mu and lv
  f32x4 accm[2], accl[2];
  #pragma unroll
  for (int b = 0; b < 2; ++b){
    accm[b] = (f32x4){0.f,0.f,0.f,0.f};
    accl[b] = (f32x4){0.f,0.f,0.f,0.f};
  }
  {
    stageB(Wcb, 256, 0, S0);
    __syncthreads();                       // gather writes + S0 staged
    for (int kt = 0; kt < 4; ++kt){
      if (kt < 3) stageB(Wcb, 256, (kt+1)*64, ((kt+1)&1) ? S1 : S0);
      const u16* as = O1 + kt * 1024;      // agg2 chunk kt
      const u16* bs = (kt & 1) ? S1 : S0;
      #pragma unroll
      for (int kk = 0; kk < 2; ++kk){
        const int ko = kk * 32 + (lane >> 4) * 8;
        short8 af = *(const short8*)(as + (lane & 15) * 64 + ko);
        #pragma unroll
        for (int ni = 0; ni < 2; ++ni){
          short8 bm = *(const short8*)(bs + (wave*32 + ni*16 + (lane & 15)) * 64 + ko);
          short8 bl = *(const short8*)(bs + (128 + wave*32 + ni*16 + (lane & 15)) * 64 + ko);
          accm[ni] = __builtin_amdgcn_mfma_f32_16x16x32_bf16(af, bm, accm[ni], 0, 0, 0);
          accl[ni] = __builtin_amdgcn_mfma_f32_16x16x32_bf16(af, bl, accl[ni], 0, 0, 0);
        }
      }
      __syncthreads();
    }
  }
  // enc epilogue: mu/lv -> global f32 (nt); h -> H chunks [2][16][64]
  {
    const int erow = (lane >> 4) << 2;
    #pragma unroll
    for (int ni = 0; ni < 2; ++ni){
      const int col = wave*32 + ni*16 + (lane & 15);
      #pragma unroll
      for (int r = 0; r < 4; ++r){
        const int lrow = erow + r;
        const size_t off = (size_t)(m0 + lrow) * 128 + col;
        const float m = fmaxf(accm[ni][r], 0.f);
        const float l = fmaxf(accl[ni][r], 0.f);
        __builtin_nontemporal_store(m, &outMu[off]);
        __builtin_nontemporal_store(l, &outLv[off]);
        H[(col >> 6) * 1024 + lrow * 64 + (col & 63)] = f2bf(eps[off] * expf(l) + m);
      }
    }
  }
  stageB(Wd1b, 128, 0, S0);
  stageB(Wd1b, 128, 64, S1);
  __syncthreads();

  const int rb = (lane >> 4) << 2;
  const int cb = wave * 64 + (lane & 15);

  // ===== D1: o1 = tanh(h @ Wd1^T + b1), K=128 =====
  {
    f32x4 acc[4];
    #pragma unroll
    for (int b = 0; b < 4; ++b) acc[b] = (f32x4){0.f,0.f,0.f,0.f};
    mstep16(H, S0, acc);
    mstep16(H + 1024, S1, acc);
    __syncthreads();
    #pragma unroll
    for (int ni = 0; ni < 4; ++ni){
      const int col = cb + ni * 16;
      const float bv = b1[col];
      #pragma unroll
      for (int r = 0; r < 4; ++r){
        const int lrow = rb + r;
        O1[(col >> 6) * 1024 + lrow * 64 + (col & 63)] = f2bf(tanhf(acc[ni][r] + bv));
      }
    }
    stageB(Wd2b, 256, 0, S0);
    __syncthreads();
  }

  // ===== D2: o2 = o1 @ Wd2^T + b2, K=256 =====
  {
    f32x4 acc[4];
    #pragma unroll
    for (int b = 0; b < 4; ++b) acc[b] = (f32x4){0.f,0.f,0.f,0.f};
    for (int c = 0; c < 4; ++c){
      if (c < 3) stageB(Wd2b, 256, (c+1)*64, ((c+1)&1) ? S1 : S0);
      mstep16(O1 + c*1024, (c&1) ? S1 : S0, acc);
      __syncthreads();
    }
    #pragma unroll
    for (int ni = 0; ni < 4; ++ni){
      const int col = cb + ni * 16;
      const float bv = b2[col];
      #pragma unroll
      for (int r = 0; r < 4; ++r){
        const int lrow = rb + r;
        O1[(col >> 6) * 1024 + lrow * 64 + (col & 63)] = f2bf(acc[ni][r] + bv);
      }
    }
    __syncthreads();
    stageB(Gtb, 256, 0, S0);     // overlap D3 staging with o2g copy
    #pragma unroll
    for (int q = 0; q < 2; ++q){
      const int e = q * 2048 + tid * 8;
      const int lrow = e >> 8, col = e & 255;
      *(u16x8*)(o2g + (size_t)(m0 + lrow) * 256 + col) =
        *(const u16x8*)(O1 + (col >> 6) * 1024 + lrow * 64 + (col & 63));
    }
    __syncthreads();
  }

  // ===== D3: tmp = o2 @ Gt^T, K=256 =====
  {
    f32x4 acc[4];
    #pragma unroll
    for (int b = 0; b < 4; ++b) acc[b] = (f32x4){0.f,0.f,0.f,0.f};
    for (int c = 0; c < 4; ++c){
      if (c < 3) stageB(Gtb, 256, (c+1)*64, ((c+1)&1) ? S1 : S0);
      mstep16(O1 + c*1024, (c&1) ? S1 : S0, acc);
      __syncthreads();
    }
    #pragma unroll
    for (int ni = 0; ni < 4; ++ni){
      const int col = cb + ni * 16;
      #pragma unroll
      for (int r = 0; r < 4; ++r){
        const int lrow = rb + r;
        tmpg[(size_t)(m0 + lrow) * 256 + col] = f2bf(acc[ni][r]);
      }
    }
  }
}

// ---------- launch ----------
extern "C" void kernel_launch(void* const* d_in, const int* in_sizes, int n_in,
                              void* d_out, int out_size, void* d_ws, size_t ws_size,
                              hipStream_t stream){
  const float* features = (const float*)d_in[0];
  const int*   neigh1   = (const int*)  d_in[1];
  const int*   neigh2   = (const int*)  d_in[2];
  const float* eps      = (const float*)d_in[3];
  const float* W1       = (const float*)d_in[4];
  const float* W2       = (const float*)d_in[5];
  const float* W3       = (const float*)d_in[6];
  const float* Wd1      = (const float*)d_in[7];
  const float* b1       = (const float*)d_in[8];
  const float* Wd2      = (const float*)d_in[9];
  const float* b2       = (const float*)d_in[10];
  const float* M1       = (const float*)d_in[11];
  const float* M2       = (const float*)d_in[12];
  float* out = (float*)d_out;
  char*  ws  = (char*)d_ws;

  u8*  FW8  = (u8*)(ws);              // fp8 FW, 12.8 MB
  u32* h18  = (u32*)(ws + 25600000);  // fp8 h1, 12.8 MB
  u16* o2g  = (u16*)(ws + 14680064);
  u16* tmpg = (u16*)(ws + 18874368);
  u16* W1b  = (u16*)(ws + 51200000);
  u16* Wcb  = W1b  + 65536;   // [W2;W3] 256x256
  u16* Wd1b = Wcb  + 65536;   // 256x128
  u16* Wd2b = Wd1b + 32768;   // 256x256
  u16* Gtb  = Wd2b + 65536;   // Gt = M2 @ M1^T

  // 1) prep: Gt (blocks 0-3) + weight converts (blocks 4-227)
  prep<<<228, 256, 0, stream>>>(M2, M1, W1, W2, W3, Wd1, Wd2,
                                Gtb, W1b, Wcb, Wd1b, Wd2b);
  // 2) FW = F @ W1^T  [50000x256] fp8 out
  fw_gemm<<<391, 256, 0, stream>>>(features, W1b, FW8, 50000);
  // 3) h1 = relu(mean(FW[neigh1]))  [50000x256] fp8
  gather_fp8<<<6250, 256, 0, stream>>>((const u32*)FW8, neigh1, h18, 50000);
  // 4) fused decoder -- LAUNCHED 3x (idempotent) to measure its duration:
  //    decoder = (dur - 158.8) / 2. Measurement round.
  decoder<<<512, 256, 0, stream>>>(h18, neigh2, Wcb, Wd1b, Wd2b, Gtb, eps, b1, b2,
                                   out, out + 1048576, o2g, tmpg);
  decoder<<<512, 256, 0, stream>>>(h18, neigh2, Wcb, Wd1b, Wd2b, Gtb, eps, b1, b2,
                                   out, out + 1048576, o2g, tmpg);
  decoder<<<512, 256, 0, stream>>>(h18, neigh2, Wcb, Wd1b, Wd2b, Gtb, eps, b1, b2,
                                   out, out + 1048576, o2g, tmpg);
  // 5) adj = tmp @ o2^T  [8192x8192] f32 (64 KB LDS, 2 blocks/CU, nt stores)
  adj_gemm<<<1024, 512, 0, stream>>>(tmpg, o2g, out + 2097152);
}

// Round 16
// 171.888 us; speedup vs baseline: 1.1791x; 1.1791x over previous
//
#include <hip/hip_runtime.h>
#include <cstdint>
#include <cstddef>

typedef unsigned short u16;
typedef unsigned int   u32;
typedef unsigned char  u8;
typedef __attribute__((ext_vector_type(8))) short short8;
typedef __attribute__((ext_vector_type(8))) u16   u16x8;
typedef __attribute__((ext_vector_type(4))) float f32x4;
typedef __attribute__((ext_vector_type(2))) float f32x2;
typedef __attribute__((ext_vector_type(4))) u16   u16x4;

// ---------- bf16 helpers (RNE) ----------
__device__ __forceinline__ float bf2f(u16 u){
  u32 x = ((u32)u) << 16; float f; __builtin_memcpy(&f, &x, 4); return f;
}
__device__ __forceinline__ u16 f2bf(float f){
  u32 x; __builtin_memcpy(&x, &f, 4);
  x += 0x7fffu + ((x >> 16) & 1u);
  return (u16)(x >> 16);
}

__device__ __forceinline__ void gload_lds16(const u16* g, u16* l){
  __builtin_amdgcn_global_load_lds((const __attribute__((address_space(1))) void*)g,
                                   (__attribute__((address_space(3))) void*)l, 16, 0, 0);
}

// ---------- fwprep: one launch does FW-GEMM + Gt-GEMM + weight converts ----------
// blocks 0-390:  FW = F @ W1^T (128x256 tile, BK=32, W1 read f32 + converted in-stage), fp8 out
// blocks 391-394: Gt = M2 @ M1^T (128^2 tile, single-buffered BK=64)
// blocks 395-554: converts W2,W3 -> Wcb; Wd1 -> Wd1b; Wd2 -> Wd2b
__global__ __launch_bounds__(256)
void fwprep(const float* __restrict__ F, const float* __restrict__ W1f,
            const float* __restrict__ M2v, const float* __restrict__ M1v,
            const float* __restrict__ W2, const float* __restrict__ W3,
            const float* __restrict__ Wd1, const float* __restrict__ Wd2,
            u8* __restrict__ FW8, u16* __restrict__ Gtb, u16* __restrict__ Wcb,
            u16* __restrict__ Wd1b, u16* __restrict__ Wd2b, int M)
{
  __shared__ u16 lds[26624];   // fw: As 2x5120 (pad40) | Bs 2x8192 ; Gt: As 8192 | Bs 8192
  const int tid  = threadIdx.x;
  const int bid  = blockIdx.x;

  if (bid >= 395){             // ---- weight converts ----
    int j = (bid - 395) * 256 + tid;
    const float* src; u16* dst;
    if (j < 8192)                 { src = W2;  dst = Wcb; }
    else if ((j -= 8192) < 8192)  { src = W3;  dst = Wcb + 32768; }
    else if ((j -= 8192) < 8192)  { src = Wd1; dst = Wd1b; }
    else { j -= 8192; src = Wd2; dst = Wd2b; }
    float4 v = ((const float4*)src)[j];
    u16x4 o; o[0]=f2bf(v.x); o[1]=f2bf(v.y); o[2]=f2bf(v.z); o[3]=f2bf(v.w);
    ((u16x4*)dst)[j] = o;
    return;
  }

  const int lane = tid & 63;
  const int wave = tid >> 6;

  if (bid >= 391){             // ---- Gt = M2 @ M1^T, single-buffered ----
    u16* As = lds;
    u16* Bs = lds + 8192;
    const int g = bid - 391;
    const int wm = wave >> 1, wn = wave & 1;
    const int m0 = (g >> 1) << 7, n0 = (g & 1) << 7;

    f32x4 acc[4][4];
    #pragma unroll
    for (int a = 0; a < 4; ++a)
      #pragma unroll
      for (int b = 0; b < 4; ++b)
        acc[a][b] = (f32x4){0.f, 0.f, 0.f, 0.f};

    for (int kt = 0; kt < 4; ++kt){
      const int k0 = kt * 64;
      const int f = tid * 32;
      {
        const float* sA = M2v + (size_t)(m0 + (f >> 6)) * 256 + k0 + (f & 63);
        u16 t[32];
        #pragma unroll
        for (int q = 0; q < 8; ++q){
          float4 v = *(const float4*)(sA + q * 4);
          t[q*4]=f2bf(v.x); t[q*4+1]=f2bf(v.y); t[q*4+2]=f2bf(v.z); t[q*4+3]=f2bf(v.w);
        }
        #pragma unroll
        for (int q = 0; q < 4; ++q)
          *(u16x8*)(&As[f + q*8]) = *(const u16x8*)(&t[q*8]);
      }
      {
        const float* sB = M1v + (size_t)(n0 + (f >> 6)) * 256 + k0 + (f & 63);
        u16 t[32];
        #pragma unroll
        for (int q = 0; q < 8; ++q){
          float4 v = *(const float4*)(sB + q * 4);
          t[q*4]=f2bf(v.x); t[q*4+1]=f2bf(v.y); t[q*4+2]=f2bf(v.z); t[q*4+3]=f2bf(v.w);
        }
        #pragma unroll
        for (int q = 0; q < 4; ++q)
          *(u16x8*)(&Bs[f + q*8]) = *(const u16x8*)(&t[q*8]);
      }
      __syncthreads();
      #pragma unroll
      for (int kk = 0; kk < 2; ++kk){
        const int ko = kk * 32 + (lane >> 4) * 8;
        short8 af[4], bq[4];
        #pragma unroll
        for (int mi = 0; mi < 4; ++mi)
          af[mi] = *(const short8*)(As + (wm*64 + mi*16 + (lane & 15)) * 64 + ko);
        #pragma unroll
        for (int ni = 0; ni < 4; ++ni)
          bq[ni] = *(const short8*)(Bs + (wn*64 + ni*16 + (lane & 15)) * 64 + ko);
        #pragma unroll
        for (int mi = 0; mi < 4; ++mi)
          #pragma unroll
          for (int ni = 0; ni < 4; ++ni)
            acc[mi][ni] = __builtin_amdgcn_mfma_f32_16x16x32_bf16(af[mi], bq[ni], acc[mi][ni], 0, 0, 0);
      }
      __syncthreads();
    }

    const int rbase = m0 + wm * 64 + ((lane >> 4) << 2);
    const int cbase = n0 + wn * 64 + (lane & 15);
    #pragma unroll
    for (int mi = 0; mi < 4; ++mi)
      #pragma unroll
      for (int ni = 0; ni < 4; ++ni){
        const int col = cbase + ni * 16;
        #pragma unroll
        for (int r = 0; r < 4; ++r)
          Gtb[(size_t)(rbase + mi * 16 + r) * 256 + col] = f2bf(acc[mi][ni][r]);
      }
    return;
  }

  // ---- FW = F @ W1^T, 128x256 tile, BK=32, fp8 out ----
  u16* As0 = lds;         u16* As1 = lds + 5120;
  u16* Bs0 = lds + 10240; u16* Bs1 = lds + 18432;
  const int wm = wave >> 1, wn = wave & 1;
  const int m0 = bid << 7;

  f32x4 acc[4][8];
  #pragma unroll
  for (int a = 0; a < 4; ++a)
    #pragma unroll
    for (int b = 0; b < 8; ++b)
      acc[a][b] = (f32x4){0.f, 0.f, 0.f, 0.f};

  auto stage = [&](int buf, int kt){
    const int k0 = kt * 32;
    u16* Ad = buf ? As1 : As0;
    u16* Bd = buf ? Bs1 : Bs0;
    // A: 128x32 f32 -> bf16, pad-40 rows (16 f32/thread)
    const int f = tid * 16;
    const int row = f >> 5, ku = f & 31;
    int ra = m0 + row; if (ra >= M) ra = M - 1;
    const float* sA = F + (size_t)ra * 256 + k0 + ku;
    u16 t[16];
    #pragma unroll
    for (int q = 0; q < 4; ++q){
      float4 v = *(const float4*)(sA + q * 4);
      t[q*4]=f2bf(v.x); t[q*4+1]=f2bf(v.y); t[q*4+2]=f2bf(v.z); t[q*4+3]=f2bf(v.w);
    }
    u16* dA = Ad + row * 40 + ku;
    *(u16x8*)(dA)     = *(const u16x8*)(&t[0]);
    *(u16x8*)(dA + 8) = *(const u16x8*)(&t[8]);
    // B: W1 f32 [256 rows][32 k] -> bf16, one row/thread, XOR-swizzled write
    const float* sB = W1f + (size_t)tid * 256 + k0;
    u16 tb[32];
    #pragma unroll
    for (int q = 0; q < 8; ++q){
      float4 v = *(const float4*)(sB + q * 4);
      tb[q*4]=f2bf(v.x); tb[q*4+1]=f2bf(v.y); tb[q*4+2]=f2bf(v.z); tb[q*4+3]=f2bf(v.w);
    }
    const int sw = (tid & 3) << 3;
    #pragma unroll
    for (int q = 0; q < 4; ++q)
      *(u16x8*)(&Bd[tid * 32 + ((q * 8) ^ sw)]) = *(const u16x8*)(&tb[q*8]);
  };

  stage(0, 0);
  __syncthreads();
  int cur = 0;
  for (int kt = 0; kt < 8; ++kt){
    if (kt + 1 < 8) stage(cur ^ 1, kt + 1);
    const u16* as = cur ? As1 : As0;
    const u16* bs = cur ? Bs1 : Bs0;
    const int ko = (lane >> 4) * 8;
    short8 af[4], bq[8];
    #pragma unroll
    for (int mi = 0; mi < 4; ++mi)
      af[mi] = *(const short8*)(as + (wm*64 + mi*16 + (lane & 15)) * 40 + ko);
    #pragma unroll
    for (int ni = 0; ni < 8; ++ni){
      const int row = wn*128 + ni*16 + (lane & 15);
      bq[ni] = *(const short8*)(bs + row * 32 + (ko ^ ((row & 3) << 3)));
    }
    #pragma unroll
    for (int mi = 0; mi < 4; ++mi)
      #pragma unroll
      for (int ni = 0; ni < 8; ++ni)
        acc[mi][ni] = __builtin_amdgcn_mfma_f32_16x16x32_bf16(af[mi], bq[ni], acc[mi][ni], 0, 0, 0);
    __syncthreads();
    cur ^= 1;
  }

  const int rbase = m0 + wm * 64 + ((lane >> 4) << 2);
  const int cbase = wn * 128 + (lane & 15);
  #pragma unroll
  for (int mi = 0; mi < 4; ++mi)
    #pragma unroll
    for (int ni = 0; ni < 8; ++ni){
      const int col = cbase + ni * 16;
      #pragma unroll
      for (int r = 0; r < 4; ++r){
        const int row = rbase + mi * 16 + r;
        if (row < M){
          const float v = acc[mi][ni][r];
          const int pk = __builtin_amdgcn_cvt_pk_fp8_f32(v, v, 0, false);
          FW8[(size_t)row * 256 + col] = (u8)(pk & 0xff);
        }
      }
    }
}

// ---------- gather-mean over 20 sampled fp8 rows + relu -> fp8 out ----------
__global__ void gather_fp8(const u32* __restrict__ rows, const int* __restrict__ idx,
                           u32* __restrict__ out, int nout){
  const int pair = blockIdx.x * 4 + (threadIdx.x >> 6);
  const int lane = threadIdx.x & 63;
  const int node0 = pair * 2;
  if (node0 >= nout) return;
  const int half = lane >> 5, l31 = lane & 31;
  const int node = node0 + half;
  const int jv = (l31 < 20) ? idx[(size_t)node * 20 + l31] : 0;
  float a[8];
  #pragma unroll
  for (int k = 0; k < 8; ++k) a[k] = 0.f;
  #pragma unroll
  for (int s = 0; s < 20; ++s){
    const int j = __shfl(jv, (lane & 32) + s, 64);
    const uint2 u = *(const uint2*)(rows + (size_t)j * 64 + l31 * 2);
    f32x2 p0 = __builtin_amdgcn_cvt_pk_f32_fp8((int)u.x, false);
    f32x2 p1 = __builtin_amdgcn_cvt_pk_f32_fp8((int)u.x, true);
    f32x2 p2 = __builtin_amdgcn_cvt_pk_f32_fp8((int)u.y, false);
    f32x2 p3 = __builtin_amdgcn_cvt_pk_f32_fp8((int)u.y, true);
    a[0]+=p0[0]; a[1]+=p0[1]; a[2]+=p1[0]; a[3]+=p1[1];
    a[4]+=p2[0]; a[5]+=p2[1]; a[6]+=p3[0]; a[7]+=p3[1];
  }
  const float inv = 0.05f;
  #pragma unroll
  for (int k = 0; k < 8; ++k) a[k] = fmaxf(a[k] * inv, 0.f);
  const int w0 = __builtin_amdgcn_cvt_pk_fp8_f32(a[0], a[1], 0, false);
  const int w1 = __builtin_amdgcn_cvt_pk_fp8_f32(a[2], a[3], 0, false);
  const int w2 = __builtin_amdgcn_cvt_pk_fp8_f32(a[4], a[5], 0, false);
  const int w3 = __builtin_amdgcn_cvt_pk_fp8_f32(a[6], a[7], 0, false);
  uint2 o;
  o.x = (w0 & 0xffffu) | ((u32)(w1 & 0xffffu) << 16);
  o.y = (w2 & 0xffffu) | ((u32)(w3 & 0xffffu) << 16);
  *(uint2*)(out + (size_t)node * 64 + l31 * 2) = o;
}

// ---------- adj = A[8192,256] @ B[8192,256]^T -> f32 [8192,8192] ----------
__global__ __launch_bounds__(512)
void adj_gemm(const u16* __restrict__ A, const u16* __restrict__ B,
              float* __restrict__ C)
{
  __shared__ __align__(16) u16 lds[32768];        // 64 KB: As 16384 | Bs 16384
  u16* As = lds;
  u16* Bs = lds + 16384;
  const int tid  = threadIdx.x;
  const int lane = tid & 63;
  const int wave = tid >> 6;
  const int wm = wave >> 2, wn = wave & 3;
  const int bid  = blockIdx.x;
  const int xcd  = bid & 7, slot = bid >> 3;
  const int m0 = ((xcd << 2) + (slot >> 5)) << 8;
  const int n0 = (slot & 31) << 8;

  f32x4 acc[8][4];
  #pragma unroll
  for (int a = 0; a < 8; ++a)
    #pragma unroll
    for (int b = 0; b < 4; ++b)
      acc[a][b] = (f32x4){0.f, 0.f, 0.f, 0.f};

  for (int kt = 0; kt < 4; ++kt){
    const int k0 = kt * 64;
    #pragma unroll
    for (int c = 0; c < 4; ++c){
      const int f = c * 4096 + tid * 8;
      const int row = f >> 6, ksw = (f & 63) ^ ((row & 7) << 3);
      gload_lds16(A + (size_t)(m0 + row) * 256 + k0 + ksw, As + f);
    }
    #pragma unroll
    for (int c = 0; c < 4; ++c){
      const int f = c * 4096 + tid * 8;
      const int row = f >> 6, ksw = (f & 63) ^ ((row & 7) << 3);
      gload_lds16(B + (size_t)(n0 + row) * 256 + k0 + ksw, Bs + f);
    }
    __syncthreads();
    #pragma unroll
    for (int kk = 0; kk < 2; ++kk){
      const int ko = kk * 32 + (lane >> 4) * 8;
      short8 af[8], bq[4];
      #pragma unroll
      for (int mi = 0; mi < 8; ++mi){
        const int row = wm*128 + mi*16 + (lane & 15);
        af[mi] = *(const short8*)(As + row * 64 + (ko ^ ((row & 7) << 3)));
      }
      #pragma unroll
      for (int ni = 0; ni < 4; ++ni){
        const int row = wn*64 + ni*16 + (lane & 15);
        bq[ni] = *(const short8*)(Bs + row * 64 + (ko ^ ((row & 7) << 3)));
      }
      #pragma unroll
      for (int mi = 0; mi < 8; ++mi)
        #pragma unroll
        for (int ni = 0; ni < 4; ++ni)
          acc[mi][ni] = __builtin_amdgcn_mfma_f32_16x16x32_bf16(af[mi], bq[ni], acc[mi][ni], 0, 0, 0);
    }
    __syncthreads();
  }

  // epilogue: 8 chunks of 32 rows via LDS transpose (T[32][260] f32 = 33 KB)
  float* T = (float*)lds;
  #pragma unroll
  for (int c = 0; c < 8; ++c){
    if (wm == (c >> 2)){
      #pragma unroll
      for (int mi2 = 0; mi2 < 2; ++mi2){
        const int mi = (c & 3) * 2 + mi2;
        #pragma unroll
        for (int ni = 0; ni < 4; ++ni){
          const int cl = wn*64 + ni*16 + (lane & 15);
          #pragma unroll
          for (int r = 0; r < 4; ++r){
            const int lr = mi2*16 + ((lane >> 4) << 2) + r;
            T[lr * 260 + cl] = acc[mi][ni][r];
          }
        }
      }
    }
    __syncthreads();
    #pragma unroll
    for (int q = 0; q < 4; ++q){
      const int g = q * 512 + tid;
      const int r = g >> 6, col = (g & 63) * 4;
      f32x4 v = *(const f32x4*)(T + r * 260 + col);
      __builtin_nontemporal_store(v, (f32x4*)(C + (size_t)(m0 + c*32 + r) * 8192 + n0 + col));
    }
    __syncthreads();
  }
}

// ---------- fused decoder: 16 rows/block, 512 blocks, single-buffered weights (44 KB -> 3/CU) ----------
__global__ __launch_bounds__(256)
void decoder(const u32* __restrict__ h1, const int* __restrict__ neigh2,
             const u16* __restrict__ Wcb,
             const u16* __restrict__ Wd1b, const u16* __restrict__ Wd2b,
             const u16* __restrict__ Gtb, const float* __restrict__ eps,
             const float* __restrict__ b1, const float* __restrict__ b2,
             float* __restrict__ outMu, float* __restrict__ outLv,
             u16* __restrict__ o2g, u16* __restrict__ tmpg)
{
  __shared__ u16 lds[22528];           // S 16384 | H 2048 | O1 4096  (44 KB)
  u16* S  = lds;
  u16* H  = lds + 16384;               // 2 chunks of 1024 (16x64)
  u16* O1 = lds + 18432;               // 4 chunks of 1024; holds agg2 during enc
  const int tid = threadIdx.x;
  const int lane = tid & 63, wave = tid >> 6;
  const int m0 = blockIdx.x << 4;      // 16 rows/block

  auto stageB = [&](const u16* G, int K, int k0){
    const int fb = wave * 4096 + lane * 8;
    #pragma unroll
    for (int c = 0; c < 8; ++c){
      int f = fb + c * 512;
      gload_lds16(G + (size_t)(f >> 6) * K + k0 + (f & 63), S + wave*4096 + c*512);
    }
  };
  auto mstep16 = [&](const u16* aC, f32x4 (&acc)[4]){
    #pragma unroll
    for (int kk = 0; kk < 2; ++kk){
      const int ko = kk * 32 + (lane >> 4) * 8;
      short8 af = *(const short8*)(aC + (lane & 15) * 64 + ko);
      #pragma unroll
      for (int ni = 0; ni < 4; ++ni){
        short8 bq = *(const short8*)(S + (wave*64 + ni*16 + (lane & 15)) * 64 + ko);
        acc[ni] = __builtin_amdgcn_mfma_f32_16x16x32_bf16(af, bq, acc[ni], 0, 0, 0);
      }
    }
  };

  // ===== in-kernel gather2 over fp8 h1: 2 nodes/wave x 2 iters -> O1 [4][16][64] =====
  {
    const int half = lane >> 5, l31 = lane & 31;
    #pragma unroll
    for (int it = 0; it < 2; ++it){
      const int lrow = it * 8 + wave * 2 + half;
      const int node = m0 + lrow;
      const int jv = (l31 < 20) ? neigh2[(size_t)node * 20 + l31] : 0;
      float a[8];
      #pragma unroll
      for (int k = 0; k < 8; ++k) a[k] = 0.f;
      #pragma unroll
      for (int s = 0; s < 20; ++s){
        const int j = __shfl(jv, (lane & 32) + s, 64);
        const uint2 u = *(const uint2*)(h1 + (size_t)j * 64 + l31 * 2);
        f32x2 p0 = __builtin_amdgcn_cvt_pk_f32_fp8((int)u.x, false);
        f32x2 p1 = __builtin_amdgcn_cvt_pk_f32_fp8((int)u.x, true);
        f32x2 p2 = __builtin_amdgcn_cvt_pk_f32_fp8((int)u.y, false);
        f32x2 p3 = __builtin_amdgcn_cvt_pk_f32_fp8((int)u.y, true);
        a[0]+=p0[0]; a[1]+=p0[1]; a[2]+=p1[0]; a[3]+=p1[1];
        a[4]+=p2[0]; a[5]+=p2[1]; a[6]+=p3[0]; a[7]+=p3[1];
      }
      const float inv = 0.05f;
      u16x8 o;
      #pragma unroll
      for (int k = 0; k < 8; ++k) o[k] = f2bf(a[k] * inv);
      const int c0 = l31 * 8;
      *(u16x8*)(O1 + (c0 >> 6) * 1024 + lrow * 64 + (c0 & 63)) = o;
    }
  }

  // ===== enc ===== wave covers cols wave*32..+31 of BOTH mu and lv
  f32x4 accm[2], accl[2];
  #pragma unroll
  for (int b = 0; b < 2; ++b){
    accm[b] = (f32x4){0.f,0.f,0.f,0.f};
    accl[b] = (f32x4){0.f,0.f,0.f,0.f};
  }
  for (int kt = 0; kt < 4; ++kt){
    stageB(Wcb, 256, kt * 64);
    __syncthreads();                    // covers gather2 writes on kt==0 too
    const u16* as = O1 + kt * 1024;
    #pragma unroll
    for (int kk = 0; kk < 2; ++kk){
      const int ko = kk * 32 + (lane >> 4) * 8;
      short8 af = *(const short8*)(as + (lane & 15) * 64 + ko);
      #pragma unroll
      for (int ni = 0; ni < 2; ++ni){
        short8 bm = *(const short8*)(S + (wave*32 + ni*16 + (lane & 15)) * 64 + ko);
        short8 bl = *(const short8*)(S + (128 + wave*32 + ni*16 + (lane & 15)) * 64 + ko);
        accm[ni] = __builtin_amdgcn_mfma_f32_16x16x32_bf16(af, bm, accm[ni], 0, 0, 0);
        accl[ni] = __builtin_amdgcn_mfma_f32_16x16x32_bf16(af, bl, accl[ni], 0, 0, 0);
      }
    }
    __syncthreads();
  }
  // enc epilogue: mu/lv -> global f32 (nt); h -> H chunks [2][16][64]
  {
    const int erow = (lane >> 4) << 2;
    #pragma unroll
    for (int ni = 0; ni < 2; ++ni){
      const int col = wave*32 + ni*16 + (lane & 15);
      #pragma unroll
      for (int r = 0; r < 4; ++r){
        const int lrow = erow + r;
        const size_t off = (size_t)(m0 + lrow) * 128 + col;
        const float m = fmaxf(accm[ni][r], 0.f);
        const float l = fmaxf(accl[ni][r], 0.f);
        __builtin_nontemporal_store(m, &outMu[off]);
        __builtin_nontemporal_store(l, &outLv[off]);
        H[(col >> 6) * 1024 + lrow * 64 + (col & 63)] = f2bf(eps[off] * expf(l) + m);
      }
    }
  }

  const int rb = (lane >> 4) << 2;
  const int cb = wave * 64 + (lane & 15);

  // ===== D1: o1 = tanh(h @ Wd1^T + b1), K=128 =====
  {
    f32x4 acc[4];
    #pragma unroll
    for (int b = 0; b < 4; ++b) acc[b] = (f32x4){0.f,0.f,0.f,0.f};
    #pragma unroll
    for (int c = 0; c < 2; ++c){
      stageB(Wd1b, 128, c * 64);
      __syncthreads();                  // also covers H writes on c==0
      mstep16(H + c * 1024, acc);
      __syncthreads();
    }
    #pragma unroll
    for (int ni = 0; ni < 4; ++ni){
      const int col = cb + ni * 16;
      const float bv = b1[col];
      #pragma unroll
      for (int r = 0; r < 4; ++r)
        O1[(col >> 6) * 1024 + (rb + r) * 64 + (col & 63)] = f2bf(tanhf(acc[ni][r] + bv));
    }
    __syncthreads();
  }

  // ===== D2: o2 = o1 @ Wd2^T + b2, K=256 =====
  {
    f32x4 acc[4];
    #pragma unroll
    for (int b = 0; b < 4; ++b) acc[b] = (f32x4){0.f,0.f,0.f,0.f};
    for (int c = 0; c < 4; ++c){
      stageB(Wd2b, 256, c * 64);
      __syncthreads();
      mstep16(O1 + c * 1024, acc);
      __syncthreads();
    }
    #pragma unroll
    for (int ni = 0; ni < 4; ++ni){
      const int col = cb + ni * 16;
      const float bv = b2[col];
      #pragma unroll
      for (int r = 0; r < 4; ++r)
        O1[(col >> 6) * 1024 + (rb + r) * 64 + (col & 63)] = f2bf(acc[ni][r] + bv);
    }
    __syncthreads();
    #pragma unroll
    for (int q = 0; q < 2; ++q){
      const int e = q * 2048 + tid * 8;
      const int lrow = e >> 8, col = e & 255;
      *(u16x8*)(o2g + (size_t)(m0 + lrow) * 256 + col) =
        *(const u16x8*)(O1 + (col >> 6) * 1024 + lrow * 64 + (col & 63));
    }
  }

  // ===== D3: tmp = o2 @ Gt^T, K=256 =====
  {
    f32x4 acc[4];
    #pragma unroll
    for (int b = 0; b < 4; ++b) acc[b] = (f32x4){0.f,0.f,0.f,0.f};
    for (int c = 0; c < 4; ++c){
      stageB(Gtb, 256, c * 64);
      __syncthreads();
      mstep16(O1 + c * 1024, acc);
      __syncthreads();
    }
    #pragma unroll
    for (int ni = 0; ni < 4; ++ni){
      const int col = cb + ni * 16;
      #pragma unroll
      for (int r = 0; r < 4; ++r)
        tmpg[(size_t)(m0 + rb + r) * 256 + col] = f2bf(acc[ni][r]);
    }
  }
}

// ---------- launch ----------
extern "C" void kernel_launch(void* const* d_in, const int* in_sizes, int n_in,
                              void* d_out, int out_size, void* d_ws, size_t ws_size,
                              hipStream_t stream){
  const float* features = (const float*)d_in[0];
  const int*   neigh1   = (const int*)  d_in[1];
  const int*   neigh2   = (const int*)  d_in[2];
  const float* eps      = (const float*)d_in[3];
  const float* W1       = (const float*)d_in[4];
  const float* W2       = (const float*)d_in[5];
  const float* W3       = (const float*)d_in[6];
  const float* Wd1      = (const float*)d_in[7];
  const float* b1       = (const float*)d_in[8];
  const float* Wd2      = (const float*)d_in[9];
  const float* b2       = (const float*)d_in[10];
  const float* M1       = (const float*)d_in[11];
  const float* M2       = (const float*)d_in[12];
  float* out = (float*)d_out;
  char*  ws  = (char*)d_ws;

  u8*  FW8  = (u8*)(ws);              // fp8 FW, 12.8 MB
  u32* h18  = (u32*)(ws + 25600000);  // fp8 h1, 12.8 MB
  u16* o2g  = (u16*)(ws + 14680064);
  u16* tmpg = (u16*)(ws + 18874368);
  u16* W1b  = (u16*)(ws + 51200000);  // unused slot kept for layout stability
  u16* Wcb  = W1b  + 65536;   // [W2;W3] 256x256
  u16* Wd1b = Wcb  + 65536;   // 256x128
  u16* Wd2b = Wd1b + 32768;   // 256x256
  u16* Gtb  = Wd2b + 65536;   // Gt = M2 @ M1^T

  // 1) fwprep: FW-GEMM (blocks 0-390) + Gt (391-394) + converts (395-554)
  fwprep<<<555, 256, 0, stream>>>(features, W1, M2, M1, W2, W3, Wd1, Wd2,
                                  FW8, Gtb, Wcb, Wd1b, Wd2b, 50000);
  // 2) h1 = relu(mean(FW[neigh1]))  [50000x256] fp8
  gather_fp8<<<6250, 256, 0, stream>>>((const u32*)FW8, neigh1, h18, 50000);
  // 3) fused decoder (gather2 + enc + reparam + D1 + D2 + D3), 3 blocks/CU
  decoder<<<512, 256, 0, stream>>>(h18, neigh2, Wcb, Wd1b, Wd2b, Gtb, eps, b1, b2,
                                   out, out + 1048576, o2g, tmpg);
  // 4) adj = tmp @ o2^T  [8192x8192] f32 (64 KB LDS, 2 blocks/CU, nt stores)
  adj_gemm<<<1024, 512, 0, stream>>>(tmpg, o2g, out + 2097152);
}

// Round 17
// 170.009 us; speedup vs baseline: 1.1922x; 1.0111x over previous
//
#include <hip/hip_runtime.h>
#include <cstdint>
#include <cstddef>

typedef unsigned short u16;
typedef unsigned int   u32;
typedef unsigned char  u8;
typedef __attribute__((ext_vector_type(8))) short short8;
typedef __attribute__((ext_vector_type(8))) u16   u16x8;
typedef __attribute__((ext_vector_type(4))) float f32x4;
typedef __attribute__((ext_vector_type(2))) float f32x2;
typedef __attribute__((ext_vector_type(4))) u16   u16x4;

// ---------- bf16 helpers (RNE) ----------
__device__ __forceinline__ float bf2f(u16 u){
  u32 x = ((u32)u) << 16; float f; __builtin_memcpy(&f, &x, 4); return f;
}
__device__ __forceinline__ u16 f2bf(float f){
  u32 x; __builtin_memcpy(&x, &f, 4);
  x += 0x7fffu + ((x >> 16) & 1u);
  return (u16)(x >> 16);
}

__device__ __forceinline__ void gload_lds16(const u16* g, u16* l){
  __builtin_amdgcn_global_load_lds((const __attribute__((address_space(1))) void*)g,
                                   (__attribute__((address_space(3))) void*)l, 16, 0, 0);
}

// ---------- fwprep: one launch does FW-GEMM + Gt-GEMM + weight converts ----------
__global__ __launch_bounds__(256)
void fwprep(const float* __restrict__ F, const float* __restrict__ W1f,
            const float* __restrict__ M2v, const float* __restrict__ M1v,
            const float* __restrict__ W2, const float* __restrict__ W3,
            const float* __restrict__ Wd1, const float* __restrict__ Wd2,
            u8* __restrict__ FW8, u16* __restrict__ Gtb, u16* __restrict__ Wcb,
            u16* __restrict__ Wd1b, u16* __restrict__ Wd2b, int M)
{
  __shared__ u16 lds[26624];
  const int tid  = threadIdx.x;
  const int bid  = blockIdx.x;

  if (bid >= 395){             // ---- weight converts ----
    int j = (bid - 395) * 256 + tid;
    const float* src; u16* dst;
    if (j < 8192)                 { src = W2;  dst = Wcb; }
    else if ((j -= 8192) < 8192)  { src = W3;  dst = Wcb + 32768; }
    else if ((j -= 8192) < 8192)  { src = Wd1; dst = Wd1b; }
    else { j -= 8192; src = Wd2; dst = Wd2b; }
    float4 v = ((const float4*)src)[j];
    u16x4 o; o[0]=f2bf(v.x); o[1]=f2bf(v.y); o[2]=f2bf(v.z); o[3]=f2bf(v.w);
    ((u16x4*)dst)[j] = o;
    return;
  }

  const int lane = tid & 63;
  const int wave = tid >> 6;

  if (bid >= 391){             // ---- Gt = M2 @ M1^T, single-buffered ----
    u16* As = lds;
    u16* Bs = lds + 8192;
    const int g = bid - 391;
    const int wm = wave >> 1, wn = wave & 1;
    const int m0 = (g >> 1) << 7, n0 = (g & 1) << 7;

    f32x4 acc[4][4];
    #pragma unroll
    for (int a = 0; a < 4; ++a)
      #pragma unroll
      for (int b = 0; b < 4; ++b)
        acc[a][b] = (f32x4){0.f, 0.f, 0.f, 0.f};

    for (int kt = 0; kt < 4; ++kt){
      const int k0 = kt * 64;
      const int f = tid * 32;
      {
        const float* sA = M2v + (size_t)(m0 + (f >> 6)) * 256 + k0 + (f & 63);
        u16 t[32];
        #pragma unroll
        for (int q = 0; q < 8; ++q){
          float4 v = *(const float4*)(sA + q * 4);
          t[q*4]=f2bf(v.x); t[q*4+1]=f2bf(v.y); t[q*4+2]=f2bf(v.z); t[q*4+3]=f2bf(v.w);
        }
        #pragma unroll
        for (int q = 0; q < 4; ++q)
          *(u16x8*)(&As[f + q*8]) = *(const u16x8*)(&t[q*8]);
      }
      {
        const float* sB = M1v + (size_t)(n0 + (f >> 6)) * 256 + k0 + (f & 63);
        u16 t[32];
        #pragma unroll
        for (int q = 0; q < 8; ++q){
          float4 v = *(const float4*)(sB + q * 4);
          t[q*4]=f2bf(v.x); t[q*4+1]=f2bf(v.y); t[q*4+2]=f2bf(v.z); t[q*4+3]=f2bf(v.w);
        }
        #pragma unroll
        for (int q = 0; q < 4; ++q)
          *(u16x8*)(&Bs[f + q*8]) = *(const u16x8*)(&t[q*8]);
      }
      __syncthreads();
      #pragma unroll
      for (int kk = 0; kk < 2; ++kk){
        const int ko = kk * 32 + (lane >> 4) * 8;
        short8 af[4], bq[4];
        #pragma unroll
        for (int mi = 0; mi < 4; ++mi)
          af[mi] = *(const short8*)(As + (wm*64 + mi*16 + (lane & 15)) * 64 + ko);
        #pragma unroll
        for (int ni = 0; ni < 4; ++ni)
          bq[ni] = *(const short8*)(Bs + (wn*64 + ni*16 + (lane & 15)) * 64 + ko);
        #pragma unroll
        for (int mi = 0; mi < 4; ++mi)
          #pragma unroll
          for (int ni = 0; ni < 4; ++ni)
            acc[mi][ni] = __builtin_amdgcn_mfma_f32_16x16x32_bf16(af[mi], bq[ni], acc[mi][ni], 0, 0, 0);
      }
      __syncthreads();
    }

    const int rbase = m0 + wm * 64 + ((lane >> 4) << 2);
    const int cbase = n0 + wn * 64 + (lane & 15);
    #pragma unroll
    for (int mi = 0; mi < 4; ++mi)
      #pragma unroll
      for (int ni = 0; ni < 4; ++ni){
        const int col = cbase + ni * 16;
        #pragma unroll
        for (int r = 0; r < 4; ++r)
          Gtb[(size_t)(rbase + mi * 16 + r) * 256 + col] = f2bf(acc[mi][ni][r]);
      }
    return;
  }

  // ---- FW = F @ W1^T, 128x256 tile, BK=32, fp8 out ----
  u16* As0 = lds;         u16* As1 = lds + 5120;
  u16* Bs0 = lds + 10240; u16* Bs1 = lds + 18432;
  const int wm = wave >> 1, wn = wave & 1;
  const int m0 = bid << 7;

  f32x4 acc[4][8];
  #pragma unroll
  for (int a = 0; a < 4; ++a)
    #pragma unroll
    for (int b = 0; b < 8; ++b)
      acc[a][b] = (f32x4){0.f, 0.f, 0.f, 0.f};

  auto stage = [&](int buf, int kt){
    const int k0 = kt * 32;
    u16* Ad = buf ? As1 : As0;
    u16* Bd = buf ? Bs1 : Bs0;
    const int f = tid * 16;
    const int row = f >> 5, ku = f & 31;
    int ra = m0 + row; if (ra >= M) ra = M - 1;
    const float* sA = F + (size_t)ra * 256 + k0 + ku;
    u16 t[16];
    #pragma unroll
    for (int q = 0; q < 4; ++q){
      float4 v = *(const float4*)(sA + q * 4);
      t[q*4]=f2bf(v.x); t[q*4+1]=f2bf(v.y); t[q*4+2]=f2bf(v.z); t[q*4+3]=f2bf(v.w);
    }
    u16* dA = Ad + row * 40 + ku;
    *(u16x8*)(dA)     = *(const u16x8*)(&t[0]);
    *(u16x8*)(dA + 8) = *(const u16x8*)(&t[8]);
    const float* sB = W1f + (size_t)tid * 256 + k0;
    u16 tb[32];
    #pragma unroll
    for (int q = 0; q < 8; ++q){
      float4 v = *(const float4*)(sB + q * 4);
      tb[q*4]=f2bf(v.x); tb[q*4+1]=f2bf(v.y); tb[q*4+2]=f2bf(v.z); tb[q*4+3]=f2bf(v.w);
    }
    const int sw = (tid & 3) << 3;
    #pragma unroll
    for (int q = 0; q < 4; ++q)
      *(u16x8*)(&Bd[tid * 32 + ((q * 8) ^ sw)]) = *(const u16x8*)(&tb[q*8]);
  };

  stage(0, 0);
  __syncthreads();
  int cur = 0;
  for (int kt = 0; kt < 8; ++kt){
    if (kt + 1 < 8) stage(cur ^ 1, kt + 1);
    const u16* as = cur ? As1 : As0;
    const u16* bs = cur ? Bs1 : Bs0;
    const int ko = (lane >> 4) * 8;
    short8 af[4], bq[8];
    #pragma unroll
    for (int mi = 0; mi < 4; ++mi)
      af[mi] = *(const short8*)(as + (wm*64 + mi*16 + (lane & 15)) * 40 + ko);
    #pragma unroll
    for (int ni = 0; ni < 8; ++ni){
      const int row = wn*128 + ni*16 + (lane & 15);
      bq[ni] = *(const short8*)(bs + row * 32 + (ko ^ ((row & 3) << 3)));
    }
    #pragma unroll
    for (int mi = 0; mi < 4; ++mi)
      #pragma unroll
      for (int ni = 0; ni < 8; ++ni)
        acc[mi][ni] = __builtin_amdgcn_mfma_f32_16x16x32_bf16(af[mi], bq[ni], acc[mi][ni], 0, 0, 0);
    __syncthreads();
    cur ^= 1;
  }

  const int rbase = m0 + wm * 64 + ((lane >> 4) << 2);
  const int cbase = wn * 128 + (lane & 15);
  #pragma unroll
  for (int mi = 0; mi < 4; ++mi)
    #pragma unroll
    for (int ni = 0; ni < 8; ++ni){
      const int col = cbase + ni * 16;
      #pragma unroll
      for (int r = 0; r < 4; ++r){
        const int row = rbase + mi * 16 + r;
        if (row < M){
          const float v = acc[mi][ni][r];
          const int pk = __builtin_amdgcn_cvt_pk_fp8_f32(v, v, 0, false);
          FW8[(size_t)row * 256 + col] = (u8)(pk & 0xff);
        }
      }
    }
}

// ---------- gather-mean over 20 sampled fp8 rows + relu -> fp8 out ----------
__global__ void gather_fp8(const u32* __restrict__ rows, const int* __restrict__ idx,
                           u32* __restrict__ out, int nout){
  const int pair = blockIdx.x * 4 + (threadIdx.x >> 6);
  const int lane = threadIdx.x & 63;
  const int node0 = pair * 2;
  if (node0 >= nout) return;
  const int half = lane >> 5, l31 = lane & 31;
  const int node = node0 + half;
  const int jv = (l31 < 20) ? idx[(size_t)node * 20 + l31] : 0;
  float a[8];
  #pragma unroll
  for (int k = 0; k < 8; ++k) a[k] = 0.f;
  #pragma unroll
  for (int s = 0; s < 20; ++s){
    const int j = __shfl(jv, (lane & 32) + s, 64);
    const uint2 u = *(const uint2*)(rows + (size_t)j * 64 + l31 * 2);
    f32x2 p0 = __builtin_amdgcn_cvt_pk_f32_fp8((int)u.x, false);
    f32x2 p1 = __builtin_amdgcn_cvt_pk_f32_fp8((int)u.x, true);
    f32x2 p2 = __builtin_amdgcn_cvt_pk_f32_fp8((int)u.y, false);
    f32x2 p3 = __builtin_amdgcn_cvt_pk_f32_fp8((int)u.y, true);
    a[0]+=p0[0]; a[1]+=p0[1]; a[2]+=p1[0]; a[3]+=p1[1];
    a[4]+=p2[0]; a[5]+=p2[1]; a[6]+=p3[0]; a[7]+=p3[1];
  }
  const float inv = 0.05f;
  #pragma unroll
  for (int k = 0; k < 8; ++k) a[k] = fmaxf(a[k] * inv, 0.f);
  const int w0 = __builtin_amdgcn_cvt_pk_fp8_f32(a[0], a[1], 0, false);
  const int w1 = __builtin_amdgcn_cvt_pk_fp8_f32(a[2], a[3], 0, false);
  const int w2 = __builtin_amdgcn_cvt_pk_fp8_f32(a[4], a[5], 0, false);
  const int w3 = __builtin_amdgcn_cvt_pk_fp8_f32(a[6], a[7], 0, false);
  uint2 o;
  o.x = (w0 & 0xffffu) | ((u32)(w1 & 0xffffu) << 16);
  o.y = (w2 & 0xffffu) | ((u32)(w3 & 0xffffu) << 16);
  *(uint2*)(out + (size_t)node * 64 + l31 * 2) = o;
}

// ---------- adj = A[8192,256] @ B[8192,256]^T -> f32 [8192,8192] ----------
__global__ __launch_bounds__(512)
void adj_gemm(const u16* __restrict__ A, const u16* __restrict__ B,
              float* __restrict__ C)
{
  __shared__ __align__(16) u16 lds[32768];        // 64 KB
  u16* As = lds;
  u16* Bs = lds + 16384;
  const int tid  = threadIdx.x;
  const int lane = tid & 63;
  const int wave = tid >> 6;
  const int wm = wave >> 2, wn = wave & 3;
  const int bid  = blockIdx.x;
  const int xcd  = bid & 7, slot = bid >> 3;
  const int m0 = ((xcd << 2) + (slot >> 5)) << 8;
  const int n0 = (slot & 31) << 8;

  f32x4 acc[8][4];
  #pragma unroll
  for (int a = 0; a < 8; ++a)
    #pragma unroll
    for (int b = 0; b < 4; ++b)
      acc[a][b] = (f32x4){0.f, 0.f, 0.f, 0.f};

  for (int kt = 0; kt < 4; ++kt){
    const int k0 = kt * 64;
    #pragma unroll
    for (int c = 0; c < 4; ++c){
      const int f = c * 4096 + tid * 8;
      const int row = f >> 6, ksw = (f & 63) ^ ((row & 7) << 3);
      gload_lds16(A + (size_t)(m0 + row) * 256 + k0 + ksw, As + f);
    }
    #pragma unroll
    for (int c = 0; c < 4; ++c){
      const int f = c * 4096 + tid * 8;
      const int row = f >> 6, ksw = (f & 63) ^ ((row & 7) << 3);
      gload_lds16(B + (size_t)(n0 + row) * 256 + k0 + ksw, Bs + f);
    }
    __syncthreads();
    #pragma unroll
    for (int kk = 0; kk < 2; ++kk){
      const int ko = kk * 32 + (lane >> 4) * 8;
      short8 af[8], bq[4];
      #pragma unroll
      for (int mi = 0; mi < 8; ++mi){
        const int row = wm*128 + mi*16 + (lane & 15);
        af[mi] = *(const short8*)(As + row * 64 + (ko ^ ((row & 7) << 3)));
      }
      #pragma unroll
      for (int ni = 0; ni < 4; ++ni){
        const int row = wn*64 + ni*16 + (lane & 15);
        bq[ni] = *(const short8*)(Bs + row * 64 + (ko ^ ((row & 7) << 3)));
      }
      #pragma unroll
      for (int mi = 0; mi < 8; ++mi)
        #pragma unroll
        for (int ni = 0; ni < 4; ++ni)
          acc[mi][ni] = __builtin_amdgcn_mfma_f32_16x16x32_bf16(af[mi], bq[ni], acc[mi][ni], 0, 0, 0);
    }
    __syncthreads();
  }

  float* T = (float*)lds;
  #pragma unroll
  for (int c = 0; c < 8; ++c){
    if (wm == (c >> 2)){
      #pragma unroll
      for (int mi2 = 0; mi2 < 2; ++mi2){
        const int mi = (c & 3) * 2 + mi2;
        #pragma unroll
        for (int ni = 0; ni < 4; ++ni){
          const int cl = wn*64 + ni*16 + (lane & 15);
          #pragma unroll
          for (int r = 0; r < 4; ++r){
            const int lr = mi2*16 + ((lane >> 4) << 2) + r;
            T[lr * 260 + cl] = acc[mi][ni][r];
          }
        }
      }
    }
    __syncthreads();
    #pragma unroll
    for (int q = 0; q < 4; ++q){
      const int g = q * 512 + tid;
      const int r = g >> 6, col = (g & 63) * 4;
      f32x4 v = *(const f32x4*)(T + r * 260 + col);
      __builtin_nontemporal_store(v, (f32x4*)(C + (size_t)(m0 + c*32 + r) * 8192 + n0 + col));
    }
    __syncthreads();
  }
}

// ---------- fused decoder: r14's double-buffered version (76 KB, 22 us measured) ----------
__global__ __launch_bounds__(256)
void decoder(const u32* __restrict__ h1, const int* __restrict__ neigh2,
             const u16* __restrict__ Wcb,
             const u16* __restrict__ Wd1b, const u16* __restrict__ Wd2b,
             const u16* __restrict__ Gtb, const float* __restrict__ eps,
             const float* __restrict__ b1, const float* __restrict__ b2,
             float* __restrict__ outMu, float* __restrict__ outLv,
             u16* __restrict__ o2g, u16* __restrict__ tmpg)
{
  __shared__ u16 lds[38912];           // S0 16384 | S1 16384 | H 2048 | O1 4096  (76 KB)
  u16* S0 = lds;
  u16* S1 = lds + 16384;
  u16* H  = lds + 32768;               // 2 chunks of 1024 (16x64)
  u16* O1 = lds + 34816;               // 4 chunks of 1024; holds agg2 during enc
  const int tid = threadIdx.x;
  const int lane = tid & 63, wave = tid >> 6;
  const int m0 = blockIdx.x << 4;      // 16 rows/block

  auto stageB = [&](const u16* G, int K, int k0, u16* dst){
    const int fb = wave * 4096 + lane * 8;
    #pragma unroll
    for (int c = 0; c < 8; ++c){
      int f = fb + c * 512;
      gload_lds16(G + (size_t)(f >> 6) * K + k0 + (f & 63), dst + wave*4096 + c*512);
    }
  };
  auto mstep16 = [&](const u16* aC, const u16* bT, f32x4 (&acc)[4]){
    #pragma unroll
    for (int kk = 0; kk < 2; ++kk){
      const int ko = kk * 32 + (lane >> 4) * 8;
      short8 af = *(const short8*)(aC + (lane & 15) * 64 + ko);
      #pragma unroll
      for (int ni = 0; ni < 4; ++ni){
        short8 bq = *(const short8*)(bT + (wave*64 + ni*16 + (lane & 15)) * 64 + ko);
        acc[ni] = __builtin_amdgcn_mfma_f32_16x16x32_bf16(af, bq, acc[ni], 0, 0, 0);
      }
    }
  };

  // ===== in-kernel gather2 over fp8 h1: 2 nodes/wave x 2 iters -> O1 [4][16][64] =====
  {
    const int half = lane >> 5, l31 = lane & 31;
    #pragma unroll
    for (int it = 0; it < 2; ++it){
      const int lrow = it * 8 + wave * 2 + half;
      const int node = m0 + lrow;
      const int jv = (l31 < 20) ? neigh2[(size_t)node * 20 + l31] : 0;
      float a[8];
      #pragma unroll
      for (int k = 0; k < 8; ++k) a[k] = 0.f;
      #pragma unroll
      for (int s = 0; s < 20; ++s){
        const int j = __shfl(jv, (lane & 32) + s, 64);
        const uint2 u = *(const uint2*)(h1 + (size_t)j * 64 + l31 * 2);
        f32x2 p0 = __builtin_amdgcn_cvt_pk_f32_fp8((int)u.x, false);
        f32x2 p1 = __builtin_amdgcn_cvt_pk_f32_fp8((int)u.x, true);
        f32x2 p2 = __builtin_amdgcn_cvt_pk_f32_fp8((int)u.y, false);
        f32x2 p3 = __builtin_amdgcn_cvt_pk_f32_fp8((int)u.y, true);
        a[0]+=p0[0]; a[1]+=p0[1]; a[2]+=p1[0]; a[3]+=p1[1];
        a[4]+=p2[0]; a[5]+=p2[1]; a[6]+=p3[0]; a[7]+=p3[1];
      }
      const float inv = 0.05f;
      u16x8 o;
      #pragma unroll
      for (int k = 0; k < 8; ++k) o[k] = f2bf(a[k] * inv);
      const int c0 = l31 * 8;
      *(u16x8*)(O1 + (c0 >> 6) * 1024 + lrow * 64 + (c0 & 63)) = o;
    }
  }

  // ===== enc =====
  f32x4 accm[2], accl[2];
  #pragma unroll
  for (int b = 0; b < 2; ++b){
    accm[b] = (f32x4){0.f,0.f,0.f,0.f};
    accl[b] = (f32x4){0.f,0.f,0.f,0.f};
  }
  {
    stageB(Wcb, 256, 0, S0);
    __syncthreads();
    for (int kt = 0; kt < 4; ++kt){
      if (kt < 3) stageB(Wcb, 256, (kt+1)*64, ((kt+1)&1) ? S1 : S0);
      const u16* as = O1 + kt * 1024;
      const u16* bs = (kt & 1) ? S1 : S0;
      #pragma unroll
      for (int kk = 0; kk < 2; ++kk){
        const int ko = kk * 32 + (lane >> 4) * 8;
        short8 af = *(const short8*)(as + (lane & 15) * 64 + ko);
        #pragma unroll
        for (int ni = 0; ni < 2; ++ni){
          short8 bm = *(const short8*)(bs + (wave*32 + ni*16 + (lane & 15)) * 64 + ko);
          short8 bl = *(const short8*)(bs + (128 + wave*32 + ni*16 + (lane & 15)) * 64 + ko);
          accm[ni] = __builtin_amdgcn_mfma_f32_16x16x32_bf16(af, bm, accm[ni], 0, 0, 0);
          accl[ni] = __builtin_amdgcn_mfma_f32_16x16x32_bf16(af, bl, accl[ni], 0, 0, 0);
        }
      }
      __syncthreads();
    }
  }
  {
    const int erow = (lane >> 4) << 2;
    #pragma unroll
    for (int ni = 0; ni < 2; ++ni){
      const int col = wave*32 + ni*16 + (lane & 15);
      #pragma unroll
      for (int r = 0; r < 4; ++r){
        const int lrow = erow + r;
        const size_t off = (size_t)(m0 + lrow) * 128 + col;
        const float m = fmaxf(accm[ni][r], 0.f);
        const float l = fmaxf(accl[ni][r], 0.f);
        __builtin_nontemporal_store(m, &outMu[off]);
        __builtin_nontemporal_store(l, &outLv[off]);
        H[(col >> 6) * 1024 + lrow * 64 + (col & 63)] = f2bf(eps[off] * expf(l) + m);
      }
    }
  }
  stageB(Wd1b, 128, 0, S0);
  stageB(Wd1b, 128, 64, S1);
  __syncthreads();

  const int rb = (lane >> 4) << 2;
  const int cb = wave * 64 + (lane & 15);

  // ===== D1 =====
  {
    f32x4 acc[4];
    #pragma unroll
    for (int b = 0; b < 4; ++b) acc[b] = (f32x4){0.f,0.f,0.f,0.f};
    mstep16(H, S0, acc);
    mstep16(H + 1024, S1, acc);
    __syncthreads();
    #pragma unroll
    for (int ni = 0; ni < 4; ++ni){
      const int col = cb + ni * 16;
      const float bv = b1[col];
      #pragma unroll
      for (int r = 0; r < 4; ++r){
        const int lrow = rb + r;
        O1[(col >> 6) * 1024 + lrow * 64 + (col & 63)] = f2bf(tanhf(acc[ni][r] + bv));
      }
    }
    stageB(Wd2b, 256, 0, S0);
    __syncthreads();
  }

  // ===== D2 =====
  {
    f32x4 acc[4];
    #pragma unroll
    for (int b = 0; b < 4; ++b) acc[b] = (f32x4){0.f,0.f,0.f,0.f};
    for (int c = 0; c < 4; ++c){
      if (c < 3) stageB(Wd2b, 256, (c+1)*64, ((c+1)&1) ? S1 : S0);
      mstep16(O1 + c*1024, (c&1) ? S1 : S0, acc);
      __syncthreads();
    }
    #pragma unroll
    for (int ni = 0; ni < 4; ++ni){
      const int col = cb + ni * 16;
      const float bv = b2[col];
      #pragma unroll
      for (int r = 0; r < 4; ++r){
        const int lrow = rb + r;
        O1[(col >> 6) * 1024 + lrow * 64 + (col & 63)] = f2bf(acc[ni][r] + bv);
      }
    }
    __syncthreads();
    stageB(Gtb, 256, 0, S0);
    #pragma unroll
    for (int q = 0; q < 2; ++q){
      const int e = q * 2048 + tid * 8;
      const int lrow = e >> 8, col = e & 255;
      *(u16x8*)(o2g + (size_t)(m0 + lrow) * 256 + col) =
        *(const u16x8*)(O1 + (col >> 6) * 1024 + lrow * 64 + (col & 63));
    }
    __syncthreads();
  }

  // ===== D3 =====
  {
    f32x4 acc[4];
    #pragma unroll
    for (int b = 0; b < 4; ++b) acc[b] = (f32x4){0.f,0.f,0.f,0.f};
    for (int c = 0; c < 4; ++c){
      if (c < 3) stageB(Gtb, 256, (c+1)*64, ((c+1)&1) ? S1 : S0);
      mstep16(O1 + c*1024, (c&1) ? S1 : S0, acc);
      __syncthreads();
    }
    #pragma unroll
    for (int ni = 0; ni < 4; ++ni){
      const int col = cb + ni * 16;
      #pragma unroll
      for (int r = 0; r < 4; ++r){
        const int lrow = rb + r;
        tmpg[(size_t)(m0 + lrow) * 256 + col] = f2bf(acc[ni][r]);
      }
    }
  }
}

// ---------- launch ----------
extern "C" void kernel_launch(void* const* d_in, const int* in_sizes, int n_in,
                              void* d_out, int out_size, void* d_ws, size_t ws_size,
                              hipStream_t stream){
  const float* features = (const float*)d_in[0];
  const int*   neigh1   = (const int*)  d_in[1];
  const int*   neigh2   = (const int*)  d_in[2];
  const float* eps      = (const float*)d_in[3];
  const float* W1       = (const float*)d_in[4];
  const float* W2       = (const float*)d_in[5];
  const float* W3       = (const float*)d_in[6];
  const float* Wd1      = (const float*)d_in[7];
  const float* b1       = (const float*)d_in[8];
  const float* Wd2      = (const float*)d_in[9];
  const float* b2       = (const float*)d_in[10];
  const float* M1       = (const float*)d_in[11];
  const float* M2       = (const float*)d_in[12];
  float* out = (float*)d_out;
  char*  ws  = (char*)d_ws;

  u8*  FW8  = (u8*)(ws);              // fp8 FW, 12.8 MB
  u32* h18  = (u32*)(ws + 25600000);  // fp8 h1, 12.8 MB
  u16* o2g  = (u16*)(ws + 14680064);
  u16* tmpg = (u16*)(ws + 18874368);
  u16* W1b  = (u16*)(ws + 51200000);
  u16* Wcb  = W1b  + 65536;   // [W2;W3] 256x256
  u16* Wd1b = Wcb  + 65536;   // 256x128
  u16* Wd2b = Wd1b + 32768;   // 256x256
  u16* Gtb  = Wd2b + 65536;   // Gt = M2 @ M1^T

  // 1) fwprep: FW-GEMM (blocks 0-390) + Gt (391-394) + converts (395-554)
  fwprep<<<555, 256, 0, stream>>>(features, W1, M2, M1, W2, W3, Wd1, Wd2,
                                  FW8, Gtb, Wcb, Wd1b, Wd2b, 50000);
  // 2) h1 = relu(mean(FW[neigh1]))  [50000x256] fp8
  gather_fp8<<<6250, 256, 0, stream>>>((const u32*)FW8, neigh1, h18, 50000);
  // 3) fused decoder (r14 double-buffered version)
  decoder<<<512, 256, 0, stream>>>(h18, neigh2, Wcb, Wd1b, Wd2b, Gtb, eps, b1, b2,
                                   out, out + 1048576, o2g, tmpg);
  // 4) adj = tmp @ o2^T  [8192x8192] f32 (64 KB LDS, 2 blocks/CU, nt stores)
  adj_gemm<<<1024, 512, 0, stream>>>(tmpg, o2g, out + 2097152);
}

// Round 18
// 158.188 us; speedup vs baseline: 1.2812x; 1.0747x over previous
//
#include <hip/hip_runtime.h>
#include <cstdint>
#include <cstddef>

typedef unsigned short u16;
typedef unsigned int   u32;
typedef unsigned char  u8;
typedef __attribute__((ext_vector_type(8))) short short8;
typedef __attribute__((ext_vector_type(8))) u16   u16x8;
typedef __attribute__((ext_vector_type(4))) float f32x4;
typedef __attribute__((ext_vector_type(2))) float f32x2;
typedef __attribute__((ext_vector_type(4))) u16   u16x4;

// ---------- bf16 helpers (RNE) ----------
__device__ __forceinline__ float bf2f(u16 u){
  u32 x = ((u32)u) << 16; float f; __builtin_memcpy(&f, &x, 4); return f;
}
__device__ __forceinline__ u16 f2bf(float f){
  u32 x; __builtin_memcpy(&x, &f, 4);
  x += 0x7fffu + ((x >> 16) & 1u);
  return (u16)(x >> 16);
}

__device__ __forceinline__ void gload_lds16(const u16* g, u16* l){
  __builtin_amdgcn_global_load_lds((const __attribute__((address_space(1))) void*)g,
                                   (__attribute__((address_space(3))) void*)l, 16, 0, 0);
}

// ---------- prep: blocks 0-3 compute Gt = M2 @ M1^T; blocks 4-227 convert weights ----------
__global__ __launch_bounds__(256)
void prep(const float* __restrict__ M2v, const float* __restrict__ M1v,
          const float* __restrict__ W1, const float* __restrict__ W2,
          const float* __restrict__ W3, const float* __restrict__ Wd1,
          const float* __restrict__ Wd2,
          u16* __restrict__ Gtb, u16* __restrict__ W1b, u16* __restrict__ Wcb,
          u16* __restrict__ Wd1b, u16* __restrict__ Wd2b)
{
  __shared__ u16 lds[32768];
  const int tid = threadIdx.x;
  if (blockIdx.x >= 4){
    int j = (blockIdx.x - 4) * 256 + tid;
    const float* src; u16* dst;
    if (j < 16384)                { src = W1;  dst = W1b; }
    else if ((j -= 16384) < 8192) { src = W2;  dst = Wcb; }
    else if ((j -= 8192)  < 8192) { src = W3;  dst = Wcb + 32768; }
    else if ((j -= 8192)  < 8192) { src = Wd1; dst = Wd1b; }
    else { j -= 8192; src = Wd2; dst = Wd2b; }
    float4 v = ((const float4*)src)[j];
    u16x4 o; o[0]=f2bf(v.x); o[1]=f2bf(v.y); o[2]=f2bf(v.z); o[3]=f2bf(v.w);
    ((u16x4*)dst)[j] = o;
    return;
  }
  u16* As0 = lds;         u16* As1 = lds + 8192;
  u16* Bs0 = lds + 16384; u16* Bs1 = lds + 24576;
  const int lane = tid & 63;
  const int wave = tid >> 6;
  const int wm = wave >> 1, wn = wave & 1;
  const int m0 = (blockIdx.x >> 1) << 7, n0 = (blockIdx.x & 1) << 7;

  f32x4 acc[4][4];
  #pragma unroll
  for (int a = 0; a < 4; ++a)
    #pragma unroll
    for (int b = 0; b < 4; ++b)
      acc[a][b] = (f32x4){0.f, 0.f, 0.f, 0.f};

  auto stage = [&](int buf, int kt){
    const int k0 = kt * 64;
    u16* Ad = buf ? As1 : As0;
    u16* Bd = buf ? Bs1 : Bs0;
    const int f = tid * 32;
    {
      const float* sA = M2v + (size_t)(m0 + (f >> 6)) * 256 + k0 + (f & 63);
      u16 t[32];
      #pragma unroll
      for (int q = 0; q < 8; ++q){
        float4 v = *(const float4*)(sA + q * 4);
        t[q*4]=f2bf(v.x); t[q*4+1]=f2bf(v.y); t[q*4+2]=f2bf(v.z); t[q*4+3]=f2bf(v.w);
      }
      #pragma unroll
      for (int q = 0; q < 4; ++q)
        *(u16x8*)(&Ad[f + q*8]) = *(const u16x8*)(&t[q*8]);
    }
    {
      const float* sB = M1v + (size_t)(n0 + (f >> 6)) * 256 + k0 + (f & 63);
      u16 t[32];
      #pragma unroll
      for (int q = 0; q < 8; ++q){
        float4 v = *(const float4*)(sB + q * 4);
        t[q*4]=f2bf(v.x); t[q*4+1]=f2bf(v.y); t[q*4+2]=f2bf(v.z); t[q*4+3]=f2bf(v.w);
      }
      #pragma unroll
      for (int q = 0; q < 4; ++q)
        *(u16x8*)(&Bd[f + q*8]) = *(const u16x8*)(&t[q*8]);
    }
  };

  stage(0, 0);
  __syncthreads();
  int cur = 0;
  for (int kt = 0; kt < 4; ++kt){
    if (kt < 3) stage(cur ^ 1, kt + 1);
    const u16* as = cur ? As1 : As0;
    const u16* bs = cur ? Bs1 : Bs0;
    #pragma unroll
    for (int kk = 0; kk < 2; ++kk){
      const int ko = kk * 32 + (lane >> 4) * 8;
      short8 af[4], bq[4];
      #pragma unroll
      for (int mi = 0; mi < 4; ++mi)
        af[mi] = *(const short8*)(as + (wm*64 + mi*16 + (lane & 15)) * 64 + ko);
      #pragma unroll
      for (int ni = 0; ni < 4; ++ni)
        bq[ni] = *(const short8*)(bs + (wn*64 + ni*16 + (lane & 15)) * 64 + ko);
      #pragma unroll
      for (int mi = 0; mi < 4; ++mi)
        #pragma unroll
        for (int ni = 0; ni < 4; ++ni)
          acc[mi][ni] = __builtin_amdgcn_mfma_f32_16x16x32_bf16(af[mi], bq[ni], acc[mi][ni], 0, 0, 0);
    }
    __syncthreads();
    cur ^= 1;
  }

  const int rbase = m0 + wm * 64 + ((lane >> 4) << 2);
  const int cbase = n0 + wn * 64 + (lane & 15);
  #pragma unroll
  for (int mi = 0; mi < 4; ++mi)
    #pragma unroll
    for (int ni = 0; ni < 4; ++ni){
      const int col = cbase + ni * 16;
      #pragma unroll
      for (int r = 0; r < 4; ++r)
        Gtb[(size_t)(rbase + mi * 16 + r) * 256 + col] = f2bf(acc[mi][ni][r]);
    }
}

// ---------- gather-mean over 20 sampled fp8 rows + relu -> fp8 out ----------
__global__ void gather_fp8(const u32* __restrict__ rows, const int* __restrict__ idx,
                           u32* __restrict__ out, int nout){
  const int pair = blockIdx.x * 4 + (threadIdx.x >> 6);
  const int lane = threadIdx.x & 63;
  const int node0 = pair * 2;
  if (node0 >= nout) return;
  const int half = lane >> 5, l31 = lane & 31;
  const int node = node0 + half;
  const int jv = (l31 < 20) ? idx[(size_t)node * 20 + l31] : 0;
  float a[8];
  #pragma unroll
  for (int k = 0; k < 8; ++k) a[k] = 0.f;
  #pragma unroll
  for (int s = 0; s < 20; ++s){
    const int j = __shfl(jv, (lane & 32) + s, 64);
    const uint2 u = *(const uint2*)(rows + (size_t)j * 64 + l31 * 2);
    f32x2 p0 = __builtin_amdgcn_cvt_pk_f32_fp8((int)u.x, false);
    f32x2 p1 = __builtin_amdgcn_cvt_pk_f32_fp8((int)u.x, true);
    f32x2 p2 = __builtin_amdgcn_cvt_pk_f32_fp8((int)u.y, false);
    f32x2 p3 = __builtin_amdgcn_cvt_pk_f32_fp8((int)u.y, true);
    a[0]+=p0[0]; a[1]+=p0[1]; a[2]+=p1[0]; a[3]+=p1[1];
    a[4]+=p2[0]; a[5]+=p2[1]; a[6]+=p3[0]; a[7]+=p3[1];
  }
  const float inv = 0.05f;
  #pragma unroll
  for (int k = 0; k < 8; ++k) a[k] = fmaxf(a[k] * inv, 0.f);
  const int w0 = __builtin_amdgcn_cvt_pk_fp8_f32(a[0], a[1], 0, false);
  const int w1 = __builtin_amdgcn_cvt_pk_fp8_f32(a[2], a[3], 0, false);
  const int w2 = __builtin_amdgcn_cvt_pk_fp8_f32(a[4], a[5], 0, false);
  const int w3 = __builtin_amdgcn_cvt_pk_fp8_f32(a[6], a[7], 0, false);
  uint2 o;
  o.x = (w0 & 0xffffu) | ((u32)(w1 & 0xffffu) << 16);
  o.y = (w2 & 0xffffu) | ((u32)(w3 & 0xffffu) << 16);
  *(uint2*)(out + (size_t)node * 64 + l31 * 2) = o;
}

// ---------- adj = A[8192,256] @ B[8192,256]^T -> f32 [8192,8192] ----------
__global__ __launch_bounds__(512)
void adj_gemm(const u16* __restrict__ A, const u16* __restrict__ B,
              float* __restrict__ C)
{
  __shared__ __align__(16) u16 lds[32768];        // 64 KB
  u16* As = lds;
  u16* Bs = lds + 16384;
  const int tid  = threadIdx.x;
  const int lane = tid & 63;
  const int wave = tid >> 6;
  const int wm = wave >> 2, wn = wave & 3;
  const int bid  = blockIdx.x;
  const int xcd  = bid & 7, slot = bid >> 3;
  const int m0 = ((xcd << 2) + (slot >> 5)) << 8;
  const int n0 = (slot & 31) << 8;

  f32x4 acc[8][4];
  #pragma unroll
  for (int a = 0; a < 8; ++a)
    #pragma unroll
    for (int b = 0; b < 4; ++b)
      acc[a][b] = (f32x4){0.f, 0.f, 0.f, 0.f};

  for (int kt = 0; kt < 4; ++kt){
    const int k0 = kt * 64;
    #pragma unroll
    for (int c = 0; c < 4; ++c){
      const int f = c * 4096 + tid * 8;
      const int row = f >> 6, ksw = (f & 63) ^ ((row & 7) << 3);
      gload_lds16(A + (size_t)(m0 + row) * 256 + k0 + ksw, As + f);
    }
    #pragma unroll
    for (int c = 0; c < 4; ++c){
      const int f = c * 4096 + tid * 8;
      const int row = f >> 6, ksw = (f & 63) ^ ((row & 7) << 3);
      gload_lds16(B + (size_t)(n0 + row) * 256 + k0 + ksw, Bs + f);
    }
    __syncthreads();
    #pragma unroll
    for (int kk = 0; kk < 2; ++kk){
      const int ko = kk * 32 + (lane >> 4) * 8;
      short8 af[8], bq[4];
      #pragma unroll
      for (int mi = 0; mi < 8; ++mi){
        const int row = wm*128 + mi*16 + (lane & 15);
        af[mi] = *(const short8*)(As + row * 64 + (ko ^ ((row & 7) << 3)));
      }
      #pragma unroll
      for (int ni = 0; ni < 4; ++ni){
        const int row = wn*64 + ni*16 + (lane & 15);
        bq[ni] = *(const short8*)(Bs + row * 64 + (ko ^ ((row & 7) << 3)));
      }
      #pragma unroll
      for (int mi = 0; mi < 8; ++mi)
        #pragma unroll
        for (int ni = 0; ni < 4; ++ni)
          acc[mi][ni] = __builtin_amdgcn_mfma_f32_16x16x32_bf16(af[mi], bq[ni], acc[mi][ni], 0, 0, 0);
    }
    __syncthreads();
  }

  float* T = (float*)lds;
  #pragma unroll
  for (int c = 0; c < 8; ++c){
    if (wm == (c >> 2)){
      #pragma unroll
      for (int mi2 = 0; mi2 < 2; ++mi2){
        const int mi = (c & 3) * 2 + mi2;
        #pragma unroll
        for (int ni = 0; ni < 4; ++ni){
          const int cl = wn*64 + ni*16 + (lane & 15);
          #pragma unroll
          for (int r = 0; r < 4; ++r){
            const int lr = mi2*16 + ((lane >> 4) << 2) + r;
            T[lr * 260 + cl] = acc[mi][ni][r];
          }
        }
      }
    }
    __syncthreads();
    #pragma unroll
    for (int q = 0; q < 4; ++q){
      const int g = q * 512 + tid;
      const int r = g >> 6, col = (g & 63) * 4;
      f32x4 v = *(const f32x4*)(T + r * 260 + col);
      __builtin_nontemporal_store(v, (f32x4*)(C + (size_t)(m0 + c*32 + r) * 8192 + n0 + col));
    }
    __syncthreads();
  }
}

// ---------- FW = F @ W1^T : 128x256 tile, BK=32, fp8 out ----------
__global__ __launch_bounds__(256)
void fw_gemm(const float* __restrict__ A, const u16* __restrict__ B,
             u8* __restrict__ C, int M)
{
  __shared__ u16 lds[26624];   // As 2x5120 (128 x pad40), Bs 2x8192 (256x32)
  u16* As0 = lds;         u16* As1 = lds + 5120;
  u16* Bs0 = lds + 10240; u16* Bs1 = lds + 18432;
  const int tid  = threadIdx.x;
  const int lane = tid & 63;
  const int wave = tid >> 6;
  const int wm = wave >> 1, wn = wave & 1;
  const int m0 = blockIdx.x << 7;

  f32x4 acc[4][8];
  #pragma unroll
  for (int a = 0; a < 4; ++a)
    #pragma unroll
    for (int b = 0; b < 8; ++b)
      acc[a][b] = (f32x4){0.f, 0.f, 0.f, 0.f};

  auto stage = [&](int buf, int kt){
    const int k0 = kt * 32;
    u16* Ad = buf ? As1 : As0;
    u16* Bd = buf ? Bs1 : Bs0;
    const int f = tid * 16;
    const int row = f >> 5, ku = f & 31;
    int ra = m0 + row; if (ra >= M) ra = M - 1;
    const float* sA = A + (size_t)ra * 256 + k0 + ku;
    u16 t[16];
    #pragma unroll
    for (int q = 0; q < 4; ++q){
      float4 v = *(const float4*)(sA + q * 4);
      t[q*4]=f2bf(v.x); t[q*4+1]=f2bf(v.y); t[q*4+2]=f2bf(v.z); t[q*4+3]=f2bf(v.w);
    }
    u16* dA = Ad + row * 40 + ku;
    *(u16x8*)(dA)     = *(const u16x8*)(&t[0]);
    *(u16x8*)(dA + 8) = *(const u16x8*)(&t[8]);
    #pragma unroll
    for (int c = 0; c < 4; ++c){
      const int g = c * 2048 + tid * 8;
      const int rb = g >> 5, kb = g & 31;
      gload_lds16(B + (size_t)rb * 256 + k0 + (kb ^ ((rb & 3) << 3)),
                  Bd + c * 2048 + wave * 512);
    }
  };

  stage(0, 0);
  __syncthreads();
  int cur = 0;
  for (int kt = 0; kt < 8; ++kt){
    if (kt + 1 < 8) stage(cur ^ 1, kt + 1);
    const u16* as = cur ? As1 : As0;
    const u16* bs = cur ? Bs1 : Bs0;
    const int ko = (lane >> 4) * 8;
    short8 af[4], bq[8];
    #pragma unroll
    for (int mi = 0; mi < 4; ++mi)
      af[mi] = *(const short8*)(as + (wm*64 + mi*16 + (lane & 15)) * 40 + ko);
    #pragma unroll
    for (int ni = 0; ni < 8; ++ni){
      const int row = wn*128 + ni*16 + (lane & 15);
      bq[ni] = *(const short8*)(bs + row * 32 + (ko ^ ((row & 3) << 3)));
    }
    #pragma unroll
    for (int mi = 0; mi < 4; ++mi)
      #pragma unroll
      for (int ni = 0; ni < 8; ++ni)
        acc[mi][ni] = __builtin_amdgcn_mfma_f32_16x16x32_bf16(af[mi], bq[ni], acc[mi][ni], 0, 0, 0);
    __syncthreads();
    cur ^= 1;
  }

  const int rbase = m0 + wm * 64 + ((lane >> 4) << 2);
  const int cbase = wn * 128 + (lane & 15);
  #pragma unroll
  for (int mi = 0; mi < 4; ++mi)
    #pragma unroll
    for (int ni = 0; ni < 8; ++ni){
      const int col = cbase + ni * 16;
      #pragma unroll
      for (int r = 0; r < 4; ++r){
        const int row = rbase + mi * 16 + r;
        if (row < M){
          const float v = acc[mi][ni][r];
          const int pk = __builtin_amdgcn_cvt_pk_fp8_f32(v, v, 0, false);
          C[(size_t)row * 256 + col] = (u8)(pk & 0xff);
        }
      }
    }
}

// ---------- fused decoder: 16 rows/block, 512 blocks x 512 threads (8 waves) ----------
// 2x phase width vs r14: each wave covers 32 output cols (16 in enc's dual-acc).
__global__ __launch_bounds__(512)
void decoder(const u32* __restrict__ h1, const int* __restrict__ neigh2,
             const u16* __restrict__ Wcb,
             const u16* __restrict__ Wd1b, const u16* __restrict__ Wd2b,
             const u16* __restrict__ Gtb, const float* __restrict__ eps,
             const float* __restrict__ b1, const float* __restrict__ b2,
             float* __restrict__ outMu, float* __restrict__ outLv,
             u16* __restrict__ o2g, u16* __restrict__ tmpg)
{
  __shared__ u16 lds[38912];           // S0 16384 | S1 16384 | H 2048 | O1 4096  (76 KB)
  u16* S0 = lds;
  u16* S1 = lds + 16384;
  u16* H  = lds + 32768;               // 2 chunks of 1024 (16x64)
  u16* O1 = lds + 34816;               // 4 chunks of 1024; holds agg2 during enc
  const int tid = threadIdx.x;
  const int lane = tid & 63, wave = tid >> 6;   // wave 0..7
  const int m0 = blockIdx.x << 4;      // 16 rows/block

  auto stageB = [&](const u16* G, int K, int k0, u16* dst){
    const int fb = wave * 2048 + lane * 8;
    #pragma unroll
    for (int c = 0; c < 4; ++c){
      int f = fb + c * 512;
      gload_lds16(G + (size_t)(f >> 6) * K + k0 + (f & 63), dst + wave*2048 + c*512);
    }
  };
  auto mstep16 = [&](const u16* aC, const u16* bT, f32x4 (&acc)[2]){
    #pragma unroll
    for (int kk = 0; kk < 2; ++kk){
      const int ko = kk * 32 + (lane >> 4) * 8;
      short8 af = *(const short8*)(aC + (lane & 15) * 64 + ko);
      #pragma unroll
      for (int ni = 0; ni < 2; ++ni){
        short8 bq = *(const short8*)(bT + (wave*32 + ni*16 + (lane & 15)) * 64 + ko);
        acc[ni] = __builtin_amdgcn_mfma_f32_16x16x32_bf16(af, bq, acc[ni], 0, 0, 0);
      }
    }
  };

  // ===== in-kernel gather2 over fp8 h1: 2 nodes/wave x 8 waves = 16 rows =====
  {
    const int half = lane >> 5, l31 = lane & 31;
    const int lrow = wave * 2 + half;             // 0..15
    const int node = m0 + lrow;
    const int jv = (l31 < 20) ? neigh2[(size_t)node * 20 + l31] : 0;
    float a[8];
    #pragma unroll
    for (int k = 0; k < 8; ++k) a[k] = 0.f;
    #pragma unroll
    for (int s = 0; s < 20; ++s){
      const int j = __shfl(jv, (lane & 32) + s, 64);
      const uint2 u = *(const uint2*)(h1 + (size_t)j * 64 + l31 * 2);
      f32x2 p0 = __builtin_amdgcn_cvt_pk_f32_fp8((int)u.x, false);
      f32x2 p1 = __builtin_amdgcn_cvt_pk_f32_fp8((int)u.x, true);
      f32x2 p2 = __builtin_amdgcn_cvt_pk_f32_fp8((int)u.y, false);
      f32x2 p3 = __builtin_amdgcn_cvt_pk_f32_fp8((int)u.y, true);
      a[0]+=p0[0]; a[1]+=p0[1]; a[2]+=p1[0]; a[3]+=p1[1];
      a[4]+=p2[0]; a[5]+=p2[1]; a[6]+=p3[0]; a[7]+=p3[1];
    }
    const float inv = 0.05f;
    u16x8 o;
    #pragma unroll
    for (int k = 0; k < 8; ++k) o[k] = f2bf(a[k] * inv);
    const int c0 = l31 * 8;
    *(u16x8*)(O1 + (c0 >> 6) * 1024 + lrow * 64 + (c0 & 63)) = o;
  }

  // ===== enc ===== wave covers cols wave*16..+15 of BOTH mu and lv
  f32x4 accm = (f32x4){0.f,0.f,0.f,0.f};
  f32x4 accl = (f32x4){0.f,0.f,0.f,0.f};
  {
    stageB(Wcb, 256, 0, S0);
    __syncthreads();                    // covers gather2 writes too
    for (int kt = 0; kt < 4; ++kt){
      if (kt < 3) stageB(Wcb, 256, (kt+1)*64, ((kt+1)&1) ? S1 : S0);
      const u16* as = O1 + kt * 1024;
      const u16* bs = (kt & 1) ? S1 : S0;
      #pragma unroll
      for (int kk = 0; kk < 2; ++kk){
        const int ko = kk * 32 + (lane >> 4) * 8;
        short8 af = *(const short8*)(as + (lane & 15) * 64 + ko);
        short8 bm = *(const short8*)(bs + (wave*16 + (lane & 15)) * 64 + ko);
        short8 bl = *(const short8*)(bs + (128 + wave*16 + (lane & 15)) * 64 + ko);
        accm = __builtin_amdgcn_mfma_f32_16x16x32_bf16(af, bm, accm, 0, 0, 0);
        accl = __builtin_amdgcn_mfma_f32_16x16x32_bf16(af, bl, accl, 0, 0, 0);
      }
      __syncthreads();
    }
  }
  // enc epilogue: mu/lv -> global f32 (nt); h -> H chunks [2][16][64]
  {
    const int erow = (lane >> 4) << 2;
    const int col = wave*16 + (lane & 15);
    #pragma unroll
    for (int r = 0; r < 4; ++r){
      const int lrow = erow + r;
      const size_t off = (size_t)(m0 + lrow) * 128 + col;
      const float m = fmaxf(accm[r], 0.f);
      const float l = fmaxf(accl[r], 0.f);
      __builtin_nontemporal_store(m, &outMu[off]);
      __builtin_nontemporal_store(l, &outLv[off]);
      H[(col >> 6) * 1024 + lrow * 64 + (col & 63)] = f2bf(eps[off] * expf(l) + m);
    }
  }
  stageB(Wd1b, 128, 0, S0);
  stageB(Wd1b, 128, 64, S1);
  __syncthreads();

  const int rb = (lane >> 4) << 2;
  const int cb = wave * 32 + (lane & 15);

  // ===== D1: o1 = tanh(h @ Wd1^T + b1), K=128 =====
  {
    f32x4 acc[2];
    acc[0] = (f32x4){0.f,0.f,0.f,0.f};
    acc[1] = (f32x4){0.f,0.f,0.f,0.f};
    mstep16(H, S0, acc);
    mstep16(H + 1024, S1, acc);
    __syncthreads();
    #pragma unroll
    for (int ni = 0; ni < 2; ++ni){
      const int col = cb + ni * 16;
      const float bv = b1[col];
      #pragma unroll
      for (int r = 0; r < 4; ++r)
        O1[(col >> 6) * 1024 + (rb + r) * 64 + (col & 63)] = f2bf(tanhf(acc[ni][r] + bv));
    }
    stageB(Wd2b, 256, 0, S0);
    __syncthreads();
  }

  // ===== D2: o2 = o1 @ Wd2^T + b2, K=256 =====
  {
    f32x4 acc[2];
    acc[0] = (f32x4){0.f,0.f,0.f,0.f};
    acc[1] = (f32x4){0.f,0.f,0.f,0.f};
    for (int c = 0; c < 4; ++c){
      if (c < 3) stageB(Wd2b, 256, (c+1)*64, ((c+1)&1) ? S1 : S0);
      mstep16(O1 + c*1024, (c&1) ? S1 : S0, acc);
      __syncthreads();
    }
    #pragma unroll
    for (int ni = 0; ni < 2; ++ni){
      const int col = cb + ni * 16;
      const float bv = b2[col];
      #pragma unroll
      for (int r = 0; r < 4; ++r)
        O1[(col >> 6) * 1024 + (rb + r) * 64 + (col & 63)] = f2bf(acc[ni][r] + bv);
    }
    __syncthreads();
    stageB(Gtb, 256, 0, S0);     // overlap D3 staging with o2g copy
    {
      const int e = tid * 8;
      const int lrow = e >> 8, col = e & 255;
      *(u16x8*)(o2g + (size_t)(m0 + lrow) * 256 + col) =
        *(const u16x8*)(O1 + (col >> 6) * 1024 + lrow * 64 + (col & 63));
    }
    __syncthreads();
  }

  // ===== D3: tmp = o2 @ Gt^T, K=256 =====
  {
    f32x4 acc[2];
    acc[0] = (f32x4){0.f,0.f,0.f,0.f};
    acc[1] = (f32x4){0.f,0.f,0.f,0.f};
    for (int c = 0; c < 4; ++c){
      if (c < 3) stageB(Gtb, 256, (c+1)*64, ((c+1)&1) ? S1 : S0);
      mstep16(O1 + c*1024, (c&1) ? S1 : S0, acc);
      __syncthreads();
    }
    #pragma unroll
    for (int ni = 0; ni < 2; ++ni){
      const int col = cb + ni * 16;
      #pragma unroll
      for (int r = 0; r < 4; ++r)
        tmpg[(size_t)(m0 + rb + r) * 256 + col] = f2bf(acc[ni][r]);
    }
  }
}

// ---------- launch ----------
extern "C" void kernel_launch(void* const* d_in, const int* in_sizes, int n_in,
                              void* d_out, int out_size, void* d_ws, size_t ws_size,
                              hipStream_t stream){
  const float* features = (const float*)d_in[0];
  const int*   neigh1   = (const int*)  d_in[1];
  const int*   neigh2   = (const int*)  d_in[2];
  const float* eps      = (const float*)d_in[3];
  const float* W1       = (const float*)d_in[4];
  const float* W2       = (const float*)d_in[5];
  const float* W3       = (const float*)d_in[6];
  const float* Wd1      = (const float*)d_in[7];
  const float* b1       = (const float*)d_in[8];
  const float* Wd2      = (const float*)d_in[9];
  const float* b2       = (const float*)d_in[10];
  const float* M1       = (const float*)d_in[11];
  const float* M2       = (const float*)d_in[12];
  float* out = (float*)d_out;
  char*  ws  = (char*)d_ws;

  u8*  FW8  = (u8*)(ws);              // fp8 FW, 12.8 MB
  u32* h18  = (u32*)(ws + 25600000);  // fp8 h1, 12.8 MB
  u16* o2g  = (u16*)(ws + 14680064);
  u16* tmpg = (u16*)(ws + 18874368);
  u16* W1b  = (u16*)(ws + 51200000);
  u16* Wcb  = W1b  + 65536;   // [W2;W3] 256x256
  u16* Wd1b = Wcb  + 65536;   // 256x128
  u16* Wd2b = Wd1b + 32768;   // 256x256
  u16* Gtb  = Wd2b + 65536;   // Gt = M2 @ M1^T

  // 1) prep: Gt (blocks 0-3) + weight converts (blocks 4-227)
  prep<<<228, 256, 0, stream>>>(M2, M1, W1, W2, W3, Wd1, Wd2,
                                Gtb, W1b, Wcb, Wd1b, Wd2b);
  // 2) FW = F @ W1^T  [50000x256] fp8 out
  fw_gemm<<<391, 256, 0, stream>>>(features, W1b, FW8, 50000);
  // 3) h1 = relu(mean(FW[neigh1]))  [50000x256] fp8
  gather_fp8<<<6250, 256, 0, stream>>>((const u32*)FW8, neigh1, h18, 50000);
  // 4) fused decoder (8 waves/block: 2x phase width)
  decoder<<<512, 512, 0, stream>>>(h18, neigh2, Wcb, Wd1b, Wd2b, Gtb, eps, b1, b2,
                                   out, out + 1048576, o2g, tmpg);
  // 5) adj = tmp @ o2^T  [8192x8192] f32 (64 KB LDS, 2 blocks/CU, nt stores)
  adj_gemm<<<1024, 512, 0, stream>>>(tmpg, o2g, out + 2097152);
}